// Round 8
// baseline (672.179 us; speedup 1.0000x reference)
//
#include <hip/hip_runtime.h>

#define N_NODES 50000
#define N_EDGES 500000
#define EMB 50
#define HID 64
#define OUTD 50
#define EDIM 28
#define HEADS 4
#define F1 256              // HEADS*HID
#define NEG 0.2f
#define EPS_SM 1e-16f
#define EPS_LN 1e-5f
#define LOG2E 1.4426950408889634f

typedef unsigned short u16;
typedef unsigned int u32;
typedef _Float16 hf;
typedef hf h2 __attribute__((ext_vector_type(2)));
typedef hf hf8 __attribute__((ext_vector_type(8)));
typedef float f4 __attribute__((ext_vector_type(4)));
typedef short s8v __attribute__((ext_vector_type(8)));   // 8 bf16 (4 VGPRs)

__device__ __forceinline__ float b2f(u16 u) { return __uint_as_float(((u32)u) << 16); }
__device__ __forceinline__ u16 f2b(float f) {
    u32 u = __float_as_uint(f);
    u32 r = (u + 0x7FFFu + ((u >> 16) & 1u)) >> 16;
    return (u16)r;
}
__device__ __forceinline__ h2 uq(u32 u) { return __builtin_bit_cast(h2, u); }
__device__ __forceinline__ u32 hpack(float a, float b) {
    h2 p = {(hf)a, (hf)b};
    return __builtin_bit_cast(u32, p);
}
__device__ __forceinline__ float lrelu(float x) { return x > 0.f ? x : NEG * x; }

// ======= init: zero cnt/cursor/S + ea->f16 rows (zero-padded to 32) + We->f16 packed
//         + emb->bf16 rows padded to 64 + att*log2e =======
__global__ void k_init(int* __restrict__ cnt, int* __restrict__ cursor, float* __restrict__ S,
                       const float* __restrict__ a, u32* __restrict__ o,
                       const float* __restrict__ We1, const float* __restrict__ We2,
                       u32* __restrict__ Weh1, u32* __restrict__ Weh2,
                       const float* __restrict__ att1, const float* __restrict__ att2,
                       float* __restrict__ atts1, float* __restrict__ atts2,
                       const float* __restrict__ emb, u16* __restrict__ embb) {
    int i = blockIdx.x * blockDim.x + threadIdx.x;
    if (i < N_NODES) cnt[i] = 0;
    else if (i < 2 * N_NODES) cursor[i - N_NODES] = 0;
    else if (i < 2 * N_NODES + 4) S[i - 2 * N_NODES] = 0.f;
    if (i < F1 * 16) {               // Weh1[k2*256+c], k2 in [0,16), zero-padded k2>=14
        int k2 = i >> 8, c = i & 255;
        Weh1[i] = (k2 < 14) ? hpack(We1[(2 * k2) * F1 + c], We1[(2 * k2 + 1) * F1 + c]) : 0u;
    } else if (i < F1 * 16 + 64 * 16) {  // Weh2[k2*64+c], k2>=14 or c>=OUTD zero-padded
        int j = i - F1 * 16;
        int k2 = j >> 6, c = j & 63;
        Weh2[j] = (k2 < 14 && c < OUTD) ? hpack(We2[(2 * k2) * OUTD + c], We2[(2 * k2 + 1) * OUTD + c]) : 0u;
    } else {
        int ja = i - (F1 * 16 + 64 * 16);
        if (ja < 256) atts1[ja] = att1[ja] * LOG2E;
        else if (ja < 320) {
            int c = ja - 256;
            atts2[c] = (c < OUTD) ? att2[c] * LOG2E : 0.f;
        }
    }
    if (i < N_NODES * 64) {          // embb[node][64] bf16, k>=EMB zero
        int node = i >> 6, k = i & 63;
        embb[i] = (k < EMB) ? f2b(emb[(size_t)node * EMB + k]) : (u16)0;
    }
    if (i < N_EDGES * 8) {           // 8 parts/row: parts 0..6 pack ea, part 7 zero-pads k=28..31
        int e = i >> 3, part = i & 7;
        if (part < 7) {
            float4 v = *(const float4*)(a + (size_t)e * EDIM + part * 4);
            *(uint2*)(o + (size_t)e * 16 + part * 2) = make_uint2(hpack(v.x, v.y), hpack(v.z, v.w));
        } else {
            *(uint2*)(o + (size_t)e * 16 + 14) = make_uint2(0u, 0u);
        }
    }
}

// ======= pack W transposed bf16 for MFMA node kernels =======
// W1: Wt1[col][k] col in [0,256), k in [0,64) (K=50 padded). W2: Wt2[col][k] col in [0,64), k in [0,256).
__global__ void k_packw(const float* __restrict__ Wl1, const float* __restrict__ Wr1,
                        u16* __restrict__ Wlt1, u16* __restrict__ Wrt1,
                        const float* __restrict__ Wl2, const float* __restrict__ Wr2,
                        u16* __restrict__ Wlt2, u16* __restrict__ Wrt2) {
    int i = blockIdx.x * blockDim.x + threadIdx.x;
    if (i < 256 * 64) {
        int c = i >> 6, k = i & 63;
        Wlt1[i] = (k < EMB) ? f2b(Wl1[k * F1 + c]) : (u16)0;
        Wrt1[i] = (k < EMB) ? f2b(Wr1[k * F1 + c]) : (u16)0;
    } else if (i < 2 * 256 * 64) {
        int j = i - 256 * 64;
        int c = j >> 8, k = j & 255;
        Wlt2[j] = (c < OUTD) ? f2b(Wl2[k * OUTD + c]) : (u16)0;
        Wrt2[j] = (c < OUTD) ? f2b(Wr2[k * OUTD + c]) : (u16)0;
    }
}

// ======================= CSR build =======================
__global__ void k_hist(const int* __restrict__ dst, int* __restrict__ cnt) {
    int e = blockIdx.x * blockDim.x + threadIdx.x;
    if (e < N_EDGES) atomicAdd(&cnt[dst[e]], 1);
}

__global__ __launch_bounds__(1024) void k_scan(const int* __restrict__ cnt, int* __restrict__ rowptr) {
    __shared__ int part[1024];
    int tid = threadIdx.x;
    const int CH = (N_NODES + 1023) / 1024;   // 49
    int beg = tid * CH;
    int end = beg + CH; if (end > N_NODES) end = N_NODES;
    int s = 0;
    for (int i = beg; i < end && i >= beg; i++) s += cnt[i];
    part[tid] = s;
    __syncthreads();
    for (int off = 1; off < 1024; off <<= 1) {
        int v = (tid >= off) ? part[tid - off] : 0;
        __syncthreads();
        part[tid] += v;
        __syncthreads();
    }
    int run = (tid == 0) ? 0 : part[tid - 1];
    for (int i = beg; i < end && i >= beg; i++) { rowptr[i] = run; run += cnt[i]; }
    if (tid == 1023) rowptr[N_NODES] = run;
}

// epk.x = e*64 (byte offset into eah rows), epk.y = src index; dstc[j] = dst node
__global__ void k_scatter(const int* __restrict__ src, const int* __restrict__ dst,
                          const int* __restrict__ rowptr, int* __restrict__ cursor,
                          int2* __restrict__ epk, int* __restrict__ dstc) {
    int e = blockIdx.x * blockDim.x + threadIdx.x;
    if (e >= N_EDGES) return;
    int d = dst[e];
    int pos = atomicAdd(&cursor[d], 1);
    int j = rowptr[d] + pos;
    epk[j] = make_int2(e << 6, src[e]);
    dstc[j] = d;
}

// ======================= partial-sum reducer =======================
__global__ __launch_bounds__(256) void k_sumpart(const float* __restrict__ P, int n, float* __restrict__ S) {
    float s1 = 0.f, s2 = 0.f;
    int stride = gridDim.x * blockDim.x;
    for (int i = blockIdx.x * blockDim.x + threadIdx.x; i < n; i += stride) {
        s1 += P[2 * i]; s2 += P[2 * i + 1];
    }
    #pragma unroll
    for (int off = 32; off; off >>= 1) { s1 += __shfl_xor(s1, off); s2 += __shfl_xor(s2, off); }
    __shared__ float w1[4], w2[4];
    int w = threadIdx.x >> 6;
    if ((threadIdx.x & 63) == 0) { w1[w] = s1; w2[w] = s2; }
    __syncthreads();
    if (threadIdx.x == 0) {
        atomicAdd(S,     w1[0] + w1[1] + w1[2] + w1[3]);
        atomicAdd(S + 1, w2[0] + w2[1] + w2[2] + w2[3]);
    }
}

// ======================= conv1 node transform via MFMA =======================
__global__ __launch_bounds__(256) void k_node1(
    const int* __restrict__ x, const u16* __restrict__ embb,
    const u16* __restrict__ Wlt, const u16* __restrict__ Wrt,
    const float* __restrict__ bl, const float* __restrict__ br,
    u16* __restrict__ xl, u16* __restrict__ xr)
{
    int w = threadIdx.x >> 6, lane = threadIdx.x & 63;
    int c = lane & 15, kg = lane >> 4;
    s8v bL[4][2], bR[4][2];
    float blv[4], brv[4];
    #pragma unroll
    for (int ct = 0; ct < 4; ct++) {
        int col = (w << 6) + (ct << 4) + c;
        #pragma unroll
        for (int ks = 0; ks < 2; ks++) {
            bL[ct][ks] = *(const s8v*)(Wlt + ((u32)col << 6) + (ks << 5) + (kg << 3));
            bR[ct][ks] = *(const s8v*)(Wrt + ((u32)col << 6) + (ks << 5) + (kg << 3));
        }
        blv[ct] = bl[col];
        brv[ct] = br[col];
    }
    const int NTILES = N_NODES / 16;   // 3125
    for (int t = blockIdx.x; t < NTILES; t += gridDim.x) {
        int nb = t << 4;
        int xi = x[nb + c];
        const u16* er = embb + ((u32)xi << 6);
        s8v a0 = *(const s8v*)(er + (kg << 3));
        s8v a1 = *(const s8v*)(er + 32 + (kg << 3));
        #pragma unroll
        for (int ct = 0; ct < 4; ct++) {
            int col = (w << 6) + (ct << 4) + c;
            f4 accL = {blv[ct], blv[ct], blv[ct], blv[ct]};
            f4 accR = {brv[ct], brv[ct], brv[ct], brv[ct]};
            accL = __builtin_amdgcn_mfma_f32_16x16x32_bf16(a0, bL[ct][0], accL, 0, 0, 0);
            accL = __builtin_amdgcn_mfma_f32_16x16x32_bf16(a1, bL[ct][1], accL, 0, 0, 0);
            accR = __builtin_amdgcn_mfma_f32_16x16x32_bf16(a0, bR[ct][0], accR, 0, 0, 0);
            accR = __builtin_amdgcn_mfma_f32_16x16x32_bf16(a1, bR[ct][1], accR, 0, 0, 0);
            #pragma unroll
            for (int i = 0; i < 4; i++) {
                int node = nb + (kg << 2) + i;
                xl[((size_t)node << 8) + col] = f2b(accL[i]);
                xr[((size_t)node << 8) + col] = f2b(accR[i]);
            }
        }
    }
}

// ======================= conv1 edge logits via MFMA (head-pair split) =======================
// One wave computes heads {2hp, 2hp+1} for 16 CSR-consecutive edges. wA = 8 frags (32 VGPR)
// -> fits 64-VGPR budget at __launch_bounds__(256,8) = 32 waves/CU for latency hiding.
__global__ __launch_bounds__(256, 8) void k_logits1(
    const int2* __restrict__ epk, const int* __restrict__ dstc,
    const u32* __restrict__ eah, const u16* __restrict__ xl, const u16* __restrict__ xr,
    const u32* __restrict__ Weh, const float* __restrict__ atts,
    float* __restrict__ Lg)
{
    int lane = threadIdx.x & 63;
    int er = lane & 15, grp = lane >> 4;
    int wslot = blockIdx.x * 4 + (threadIdx.x >> 6);
    int hp = wslot & 1;                 // head pair: heads 2hp, 2hp+1
    int cb = hp << 7;                   // col base 0 or 128
    hf8 wA[8];
    #pragma unroll
    for (int ct = 0; ct < 8; ct++) {
        uint4 q;
        q.x = Weh[(grp * 4 + 0) * 256 + cb + ct * 16 + er];
        q.y = Weh[(grp * 4 + 1) * 256 + cb + ct * 16 + er];
        q.z = Weh[(grp * 4 + 2) * 256 + cb + ct * 16 + er];
        q.w = Weh[(grp * 4 + 3) * 256 + cb + ct * 16 + er];
        wA[ct] = __builtin_bit_cast(hf8, q);
    }
    int wt = wslot >> 1;
    int nwt = (gridDim.x * 4) >> 1;
    const char* eab = (const char*)eah;
    const f4 zero = {0.f, 0.f, 0.f, 0.f};
    for (int t = wt; t < N_EDGES / 16; t += nwt) {
        int j = t * 16 + er;
        int2 p = epk[j];
        int d = dstc[j];
        hf8 bfrag = *(const hf8*)(eab + (u32)p.x + (grp << 4));
        const u16* xlp = xl + ((u32)p.y << 8) + cb;
        const u16* xrp = xr + ((u32)d << 8) + cb;
        float part0 = 0.f, part1 = 0.f;
        #pragma unroll
        for (int ct = 0; ct < 8; ct++) {
            int c0 = ct * 16 + grp * 4;          // within the 128-col half
            f4 z = __builtin_amdgcn_mfma_f32_16x16x32_f16(wA[ct], bfrag, zero, 0, 0, 0);
            uint2 ql = *(const uint2*)(xlp + c0);
            uint2 qr = *(const uint2*)(xrp + c0);
            float4 av = *(const float4*)(atts + cb + c0);
            float z0 = z[0] + __uint_as_float(ql.x << 16)        + __uint_as_float(qr.x << 16);
            float z1 = z[1] + __uint_as_float(ql.x & 0xFFFF0000u) + __uint_as_float(qr.x & 0xFFFF0000u);
            float z2 = z[2] + __uint_as_float(ql.y << 16)        + __uint_as_float(qr.y << 16);
            float z3 = z[3] + __uint_as_float(ql.y & 0xFFFF0000u) + __uint_as_float(qr.y & 0xFFFF0000u);
            float s = av.x * fmaxf(z0, NEG * z0) + av.y * fmaxf(z1, NEG * z1)
                    + av.z * fmaxf(z2, NEG * z2) + av.w * fmaxf(z3, NEG * z3);
            if (ct < 4) part0 += s; else part1 += s;
        }
        part0 += __shfl_xor(part0, 16); part0 += __shfl_xor(part0, 32);
        part1 += __shfl_xor(part1, 16); part1 += __shfl_xor(part1, 32);
        if (grp < 2) {
            float v = (grp & 1) ? part1 : part0;
            Lg[((size_t)j << 2) + (hp << 1) + (grp & 1)] = v;
        }
    }
}

// ======================= conv1 fused (light): softmax + aggregate only ===========
__global__ __launch_bounds__(256) void k_fused1(
    const int* __restrict__ rowptr, const int2* __restrict__ epk,
    const float* __restrict__ Lg, const u16* __restrict__ xl,
    const float* __restrict__ bias, u16* __restrict__ out, float* __restrict__ Spart)
{
    int node = blockIdx.x;
    int tid = threadIdx.x;          // global column 0..255
    int h = tid >> 6, lane = tid & 63;
    int beg = rowptr[node], end = rowptr[node + 1];
    float acc = 0.f, dtot = 0.f;
    int j = beg;
    for (; j + 3 < end; j += 4) {
        int2 pA = epk[j], pB = epk[j + 1], pC = epk[j + 2], pD = epk[j + 3];
        float g1 = Lg[((size_t)j << 2) + h];
        float g2 = Lg[((size_t)j << 2) + 4 + h];
        float g3 = Lg[((size_t)j << 2) + 8 + h];
        float g4 = Lg[((size_t)j << 2) + 12 + h];
        float xA = b2f(xl[((u32)pA.y << 8) + tid]);
        float xB = b2f(xl[((u32)pB.y << 8) + tid]);
        float xC = b2f(xl[((u32)pC.y << 8) + tid]);
        float xD = b2f(xl[((u32)pD.y << 8) + tid]);
        float p1 = exp2f(g1), p2 = exp2f(g2), p3 = exp2f(g3), p4 = exp2f(g4);
        acc  += (p1 * xA + p2 * xB) + (p3 * xC + p4 * xD);
        dtot += (p1 + p2) + (p3 + p4);
    }
    for (; j < end; j++) {
        int2 p = epk[j];
        float pe = exp2f(Lg[((size_t)j << 2) + h]);
        float xA = b2f(xl[((u32)p.y << 8) + tid]);
        acc += pe * xA; dtot += pe;
    }
    float o = ((end > beg) ? acc / (dtot + EPS_SM) : 0.f) + bias[tid];
    out[((size_t)node << 8) + tid] = f2b(o);
    float s1 = o, s2 = o * o;
    #pragma unroll
    for (int off = 32; off; off >>= 1) { s1 += __shfl_xor(s1, off); s2 += __shfl_xor(s2, off); }
    __shared__ float ls1[4], ls2[4];
    if (lane == 0) { ls1[h] = s1; ls2[h] = s2; }
    __syncthreads();
    if (tid == 0) {
        Spart[(size_t)node * 2]     = ls1[0] + ls1[1] + ls1[2] + ls1[3];
        Spart[(size_t)node * 2 + 1] = ls2[0] + ls2[1] + ls2[2] + ls2[3];
    }
}

// ======================= LayerNorm apply (+ReLU) in-place on bf16 =======================
__global__ void k_ln_apply_relu_b(
    u16* v, const float* __restrict__ w, const float* __restrict__ b,
    const float* __restrict__ S, int M, int C)
{
    int i = blockIdx.x * blockDim.x + threadIdx.x;
    if (i >= M) return;
    float mu = S[0] / (float)M;
    float var = S[1] / (float)M - mu * mu;
    float inv = 1.f / (sqrtf(fmaxf(var, 0.f)) + EPS_LN);
    int c = i % C;
    float y = (b2f(v[i]) - mu) * inv * w[c] + b[c];
    v[i] = f2b(fmaxf(y, 0.f));
}

__global__ void k_ln_out(
    const float* __restrict__ v, const float* __restrict__ w, const float* __restrict__ b,
    const float* __restrict__ S, int M, int C, float* __restrict__ out)
{
    int i = blockIdx.x * blockDim.x + threadIdx.x;
    if (i >= M) return;
    float mu = S[0] / (float)M;
    float var = S[1] / (float)M - mu * mu;
    float inv = 1.f / (sqrtf(fmaxf(var, 0.f)) + EPS_LN);
    int c = i % C;
    out[i] = (v[i] - mu) * inv * w[c] + b[c];
}

// ======================= conv2 node transform via MFMA (bf16 rows padded to 64) =========
__global__ __launch_bounds__(256) void k_node2(
    const u16* __restrict__ h, const u16* __restrict__ Wlt, const u16* __restrict__ Wrt,
    const float* __restrict__ bl, const float* __restrict__ br,
    u16* __restrict__ xlb, u16* __restrict__ xrb)
{
    int w = threadIdx.x >> 6, lane = threadIdx.x & 63;
    int c = lane & 15, kg = lane >> 4;
    int col = (w << 4) + c;                       // 0..63
    s8v bL[8], bR[8];
    #pragma unroll
    for (int ks = 0; ks < 8; ks++) {
        bL[ks] = *(const s8v*)(Wlt + ((u32)col << 8) + (ks << 5) + (kg << 3));
        bR[ks] = *(const s8v*)(Wrt + ((u32)col << 8) + (ks << 5) + (kg << 3));
    }
    float blv = (col < OUTD) ? bl[col] : 0.f;
    float brv = (col < OUTD) ? br[col] : 0.f;
    const int NTILES = N_NODES / 16;   // 3125
    for (int t = blockIdx.x; t < NTILES; t += gridDim.x) {
        int nb = t << 4;
        const u16* hrow = h + ((size_t)(nb + c) << 8) + (kg << 3);
        f4 accL = {blv, blv, blv, blv};
        f4 accR = {brv, brv, brv, brv};
        #pragma unroll
        for (int ks = 0; ks < 8; ks++) {
            s8v a = *(const s8v*)(hrow + (ks << 5));
            accL = __builtin_amdgcn_mfma_f32_16x16x32_bf16(a, bL[ks], accL, 0, 0, 0);
            accR = __builtin_amdgcn_mfma_f32_16x16x32_bf16(a, bR[ks], accR, 0, 0, 0);
        }
        #pragma unroll
        for (int i = 0; i < 4; i++) {
            int node = nb + (kg << 2) + i;
            xlb[((u32)node << 6) + col] = f2b(accL[i]);
            xrb[((u32)node << 6) + col] = f2b(accR[i]);
        }
    }
}

// ======================= conv2 edge logits via MFMA (1 head, 64 padded cols) ==========
__global__ __launch_bounds__(256) void k_logits2(
    const int2* __restrict__ epk, const int* __restrict__ dstc,
    const u32* __restrict__ eah, const u16* __restrict__ xlb, const u16* __restrict__ xrb,
    const u32* __restrict__ Weh, const float* __restrict__ atts,
    float* __restrict__ Lg2)
{
    int lane = threadIdx.x & 63;
    int er = lane & 15, grp = lane >> 4;
    hf8 wA[4];
    #pragma unroll
    for (int ct = 0; ct < 4; ct++) {
        uint4 q;
        q.x = Weh[(grp * 4 + 0) * 64 + ct * 16 + er];
        q.y = Weh[(grp * 4 + 1) * 64 + ct * 16 + er];
        q.z = Weh[(grp * 4 + 2) * 64 + ct * 16 + er];
        q.w = Weh[(grp * 4 + 3) * 64 + ct * 16 + er];
        wA[ct] = __builtin_bit_cast(hf8, q);
    }
    int wid = blockIdx.x * 4 + (threadIdx.x >> 6);
    int nw = gridDim.x * 4;
    const char* eab = (const char*)eah;
    const f4 zero = {0.f, 0.f, 0.f, 0.f};
    for (int t = wid; t < N_EDGES / 16; t += nw) {
        int j = t * 16 + er;
        int2 p = epk[j];
        int d = dstc[j];
        hf8 bfrag = *(const hf8*)(eab + (u32)p.x + (grp << 4));
        const u16* xlp = xlb + ((u32)p.y << 6);
        const u16* xrp = xrb + ((u32)d << 6);
        float tot = 0.f;
        #pragma unroll
        for (int ct = 0; ct < 4; ct++) {
            int c0 = ct * 16 + grp * 4;
            f4 z = __builtin_amdgcn_mfma_f32_16x16x32_f16(wA[ct], bfrag, zero, 0, 0, 0);
            uint2 ql = *(const uint2*)(xlp + c0);
            uint2 qr = *(const uint2*)(xrp + c0);
            float4 av = *(const float4*)(atts + c0);
            float z0 = z[0] + __uint_as_float(ql.x << 16)        + __uint_as_float(qr.x << 16);
            float z1 = z[1] + __uint_as_float(ql.x & 0xFFFF0000u) + __uint_as_float(qr.x & 0xFFFF0000u);
            float z2 = z[2] + __uint_as_float(ql.y << 16)        + __uint_as_float(qr.y << 16);
            float z3 = z[3] + __uint_as_float(ql.y & 0xFFFF0000u) + __uint_as_float(qr.y & 0xFFFF0000u);
            tot += av.x * fmaxf(z0, NEG * z0) + av.y * fmaxf(z1, NEG * z1)
                 + av.z * fmaxf(z2, NEG * z2) + av.w * fmaxf(z3, NEG * z3);
        }
        tot += __shfl_xor(tot, 16);
        tot += __shfl_xor(tot, 32);
        if (lane < 16) Lg2[j] = tot;   // 64B coalesced per tile
    }
}

// ======================= conv2 fused (light): softmax + aggregate only ===========
__global__ __launch_bounds__(256) void k_fused2(
    const int* __restrict__ rowptr, const int2* __restrict__ epk,
    const float* __restrict__ Lg2, const u16* __restrict__ xlb,
    const float* __restrict__ bias, float* __restrict__ out, float* __restrict__ Spart)
{
    int w = threadIdx.x >> 6, lane = threadIdx.x & 63;
    int node = blockIdx.x * 4 + w;
    bool col = lane < OUTD;
    int beg = rowptr[node], end = rowptr[node + 1];
    float acc = 0.f, dtot = 0.f;
    int j = beg;
    for (; j + 3 < end; j += 4) {
        int2 p0 = epk[j], p1 = epk[j + 1], p2 = epk[j + 2], p3 = epk[j + 3];
        float g0 = Lg2[j], g1 = Lg2[j + 1], g2 = Lg2[j + 2], g3 = Lg2[j + 3];
        float x0 = b2f(xlb[((u32)p0.y << 6) + lane]);
        float x1 = b2f(xlb[((u32)p1.y << 6) + lane]);
        float x2 = b2f(xlb[((u32)p2.y << 6) + lane]);
        float x3 = b2f(xlb[((u32)p3.y << 6) + lane]);
        float e0 = exp2f(g0), e1 = exp2f(g1), e2 = exp2f(g2), e3 = exp2f(g3);
        acc  += (e0 * x0 + e1 * x1) + (e2 * x2 + e3 * x3);
        dtot += (e0 + e1) + (e2 + e3);
    }
    for (; j < end; j++) {
        int2 p = epk[j];
        float e = exp2f(Lg2[j]);
        float xv = b2f(xlb[((u32)p.y << 6) + lane]);
        acc += e * xv; dtot += e;
    }
    float s1 = 0.f, s2 = 0.f;
    if (col) {
        float o = ((end > beg) ? acc / (dtot + EPS_SM) : 0.f) + bias[lane];
        out[(u32)node * OUTD + lane] = o;
        s1 = o; s2 = o * o;
    }
    #pragma unroll
    for (int off = 32; off; off >>= 1) { s1 += __shfl_xor(s1, off); s2 += __shfl_xor(s2, off); }
    __shared__ float ls1[4], ls2[4];
    if (lane == 0) { ls1[w] = s1; ls2[w] = s2; }
    __syncthreads();
    if (threadIdx.x == 0) {
        Spart[(size_t)blockIdx.x * 2]     = ls1[0] + ls1[1] + ls1[2] + ls1[3];
        Spart[(size_t)blockIdx.x * 2 + 1] = ls2[0] + ls2[1] + ls2[2] + ls2[3];
    }
}

extern "C" void kernel_launch(void* const* d_in, const int* in_sizes, int n_in,
                              void* d_out, int out_size, void* d_ws, size_t ws_size,
                              hipStream_t stream)
{
    const int*   x    = (const int*)d_in[0];
    const int*   ei   = (const int*)d_in[1];
    const int*   srcA = ei;
    const int*   dstA = ei + N_EDGES;
    const float* ea   = (const float*)d_in[2];
    const float* emb  = (const float*)d_in[3];
    const float* Wl1  = (const float*)d_in[4];
    const float* bl1  = (const float*)d_in[5];
    const float* Wr1  = (const float*)d_in[6];
    const float* br1  = (const float*)d_in[7];
    const float* We1  = (const float*)d_in[8];
    const float* att1 = (const float*)d_in[9];
    const float* bias1= (const float*)d_in[10];
    const float* ln1w = (const float*)d_in[11];
    const float* ln1b = (const float*)d_in[12];
    const float* Wl2  = (const float*)d_in[13];
    const float* bl2  = (const float*)d_in[14];
    const float* Wr2  = (const float*)d_in[15];
    const float* br2  = (const float*)d_in[16];
    const float* We2  = (const float*)d_in[17];
    const float* att2 = (const float*)d_in[18];
    const float* bias2= (const float*)d_in[19];
    const float* ln2w = (const float*)d_in[20];
    const float* ln2b = (const float*)d_in[21];

    // workspace layout (float-slot offsets); peak 31,000,000 slots = 124.0 MB
    float* W = (float*)d_ws;
    u16*   xl1b    = (u16*)W;                      // [0, 6.4M)
    u16*   xr1b    = (u16*)(W + 6400000);          // [6.4M, 12.8M)
    u16*   out1b   = (u16*)(W + 12800000);         // [12.8M, 19.2M)  bf16, h1 in place
    u32*   eah     = (u32*)(W + 19200000);         // E*16 u32 [19.2M, 27.2M)
    int2*  epk     = (int2*)(W + 27200000);        // [27.2M, 28.2M)
    int*   rowptr  = (int*)(W + 28200000);         // 50,001 ints, 60k slots
    int*   cnt     = (int*)(W + 28260000);         // N
    int*   cursor  = (int*)(W + 28310000);         // N
    float* Spart   = W + 28360000;                 // 2*N
    float* S       = W + 28460000;                 // 4
    u32*   Weh1    = (u32*)(W + 28470000);         // 16*256 = 4096 (k2>=14 zero)
    u32*   Weh2    = (u32*)(W + 28480000);         // 16*64  = 1024 (padded)
    float* atts1   = W + 28481100;                 // 256
    float* atts2   = W + 28481600;                 // 64
    int*   dstc    = (int*)(W + 28482000);         // E ints = 500k slots [28.482M, 28.982M)
    u16*   Wlt2    = (u16*)(W + 28982000);         // 64*256 u16 = 8192 slots [28.982M, 28.9902M)
    u16*   Wrt2    = (u16*)(W + 28991000);         // 64*256 u16 = 8192 slots [28.991M, 28.9992M)
    float* Lg      = W + 29000000;                 // E*4 f32 [29M, 31M)  (conv1, written by logits1)
    // pre-conv1 transients (dead before logits1 writes Lg; parked inside Lg region):
    u16*   embb    = (u16*)(W + 29000000);         // N*64 u16 = 1.6M slots [29.0M, 30.6M)
    u16*   Wlt1    = (u16*)(W + 30600000);         // 256*64 u16 = 8192 slots [30.6M, 30.6082M)
    u16*   Wrt1    = (u16*)(W + 30610000);         // 256*64 u16 = 8192 slots [30.61M, 30.6182M)
    // conv2 reuse (liveness: xl1b/xr1b dead after fused1; Lg dead after fused1):
    u16*   xl2b    = (u16*)W;                      // N*64 u16 [0, 1.6M)
    u16*   xr2b    = (u16*)(W + 1600000);          // N*64 u16 [1.6M, 3.2M)
    float* out2    = W + 3200000;                  // N*50 f32 [3.2M, 5.7M)
    float* Lg2     = W + 29000000;                 // E f32 (reuses Lg region)
    u16*   h1      = out1b;

    // init (zeroing + ea f16 + We f16 pack + emb bf16 pack + att*log2e) + W transpose pack + CSR
    k_init<<<(N_EDGES * 8 + 255) / 256, 256, 0, stream>>>(cnt, cursor, S, ea, eah,
                                                          We1, We2, Weh1, Weh2,
                                                          att1, att2, atts1, atts2,
                                                          emb, embb);
    k_packw<<<128, 256, 0, stream>>>(Wl1, Wr1, Wlt1, Wrt1, Wl2, Wr2, Wlt2, Wrt2);
    k_hist<<<(N_EDGES + 255) / 256, 256, 0, stream>>>(dstA, cnt);
    k_scan<<<1, 1024, 0, stream>>>(cnt, rowptr);
    k_scatter<<<(N_EDGES + 255) / 256, 256, 0, stream>>>(srcA, dstA, rowptr, cursor, epk, dstc);

    // conv1
    k_node1<<<1024, 256, 0, stream>>>(x, embb, Wlt1, Wrt1, bl1, br1, xl1b, xr1b);
    k_logits1<<<2048, 256, 0, stream>>>(epk, dstc, eah, xl1b, xr1b, Weh1, atts1, Lg);
    k_fused1<<<N_NODES, 256, 0, stream>>>(rowptr, epk, Lg, xl1b, bias1, out1b, Spart);
    k_sumpart<<<32, 256, 0, stream>>>(Spart, N_NODES, S);
    k_ln_apply_relu_b<<<(N_NODES * F1 + 255) / 256, 256, 0, stream>>>(h1, ln1w, ln1b, S, N_NODES * F1, F1);

    // conv2
    k_node2<<<1024, 256, 0, stream>>>(h1, Wlt2, Wrt2, bl2, br2, xl2b, xr2b);
    k_logits2<<<1024, 256, 0, stream>>>(epk, dstc, eah, xl2b, xr2b, Weh2, atts2, Lg2);
    k_fused2<<<N_NODES / 4, 256, 0, stream>>>(rowptr, epk, Lg2, xl2b, bias2, out2, Spart);
    k_sumpart<<<32, 256, 0, stream>>>(Spart, N_NODES / 4, S + 2);
    k_ln_out<<<(N_NODES * OUTD + 255) / 256, 256, 0, stream>>>(out2, ln2w, ln2b, S + 2, N_NODES * OUTD, OUTD, (float*)d_out);
}

// Round 9
// 615.615 us; speedup vs baseline: 1.0919x; 1.0919x over previous
//
#include <hip/hip_runtime.h>

#define N_NODES 50000
#define N_EDGES 500000
#define EMB 50
#define HID 64
#define OUTD 50
#define EDIM 28
#define HEADS 4
#define F1 256              // HEADS*HID
#define NEG 0.2f
#define EPS_SM 1e-16f
#define EPS_LN 1e-5f
#define LOG2E 1.4426950408889634f

typedef unsigned short u16;
typedef unsigned int u32;
typedef _Float16 hf;
typedef hf h2 __attribute__((ext_vector_type(2)));
typedef hf hf8 __attribute__((ext_vector_type(8)));
typedef float f4 __attribute__((ext_vector_type(4)));
typedef short s8v __attribute__((ext_vector_type(8)));   // 8 bf16 (4 VGPRs)

__device__ __forceinline__ float b2f(u16 u) { return __uint_as_float(((u32)u) << 16); }
__device__ __forceinline__ u16 f2b(float f) {
    u32 u = __float_as_uint(f);
    u32 r = (u + 0x7FFFu + ((u >> 16) & 1u)) >> 16;
    return (u16)r;
}
__device__ __forceinline__ h2 uq(u32 u) { return __builtin_bit_cast(h2, u); }
__device__ __forceinline__ u32 hpack(float a, float b) {
    h2 p = {(hf)a, (hf)b};
    return __builtin_bit_cast(u32, p);
}
__device__ __forceinline__ float lrelu(float x) { return x > 0.f ? x : NEG * x; }

// ======= init: zero cnt/cursor/S + We->f16 packed + emb->bf16 rows padded to 64 + att*log2e
//         (edge features now packed CSR-ordered by k_reorder) =======
__global__ void k_init(int* __restrict__ cnt, int* __restrict__ cursor, float* __restrict__ S,
                       const float* __restrict__ We1, const float* __restrict__ We2,
                       u32* __restrict__ Weh1, u32* __restrict__ Weh2,
                       const float* __restrict__ att1, const float* __restrict__ att2,
                       float* __restrict__ atts1, float* __restrict__ atts2,
                       const float* __restrict__ emb, u16* __restrict__ embb) {
    int i = blockIdx.x * blockDim.x + threadIdx.x;
    if (i < N_NODES) cnt[i] = 0;
    else if (i < 2 * N_NODES) cursor[i - N_NODES] = 0;
    else if (i < 2 * N_NODES + 4) S[i - 2 * N_NODES] = 0.f;
    if (i < F1 * 16) {               // Weh1[k2*256+c], k2 in [0,16), zero-padded k2>=14
        int k2 = i >> 8, c = i & 255;
        Weh1[i] = (k2 < 14) ? hpack(We1[(2 * k2) * F1 + c], We1[(2 * k2 + 1) * F1 + c]) : 0u;
    } else if (i < F1 * 16 + 64 * 16) {  // Weh2[k2*64+c], k2>=14 or c>=OUTD zero-padded
        int j = i - F1 * 16;
        int k2 = j >> 6, c = j & 63;
        Weh2[j] = (k2 < 14 && c < OUTD) ? hpack(We2[(2 * k2) * OUTD + c], We2[(2 * k2 + 1) * OUTD + c]) : 0u;
    } else {
        int ja = i - (F1 * 16 + 64 * 16);
        if (ja < 256) atts1[ja] = att1[ja] * LOG2E;
        else if (ja < 320) {
            int c = ja - 256;
            atts2[c] = (c < OUTD) ? att2[c] * LOG2E : 0.f;
        }
    }
    if (i < N_NODES * 64) {          // embb[node][64] bf16, k>=EMB zero
        int node = i >> 6, k = i & 63;
        embb[i] = (k < EMB) ? f2b(emb[(size_t)node * EMB + k]) : (u16)0;
    }
}

// ======= pack W transposed bf16 for MFMA node kernels =======
__global__ void k_packw(const float* __restrict__ Wl1, const float* __restrict__ Wr1,
                        u16* __restrict__ Wlt1, u16* __restrict__ Wrt1,
                        const float* __restrict__ Wl2, const float* __restrict__ Wr2,
                        u16* __restrict__ Wlt2, u16* __restrict__ Wrt2) {
    int i = blockIdx.x * blockDim.x + threadIdx.x;
    if (i < 256 * 64) {
        int c = i >> 6, k = i & 63;
        Wlt1[i] = (k < EMB) ? f2b(Wl1[k * F1 + c]) : (u16)0;
        Wrt1[i] = (k < EMB) ? f2b(Wr1[k * F1 + c]) : (u16)0;
    } else if (i < 2 * 256 * 64) {
        int j = i - 256 * 64;
        int c = j >> 8, k = j & 255;
        Wlt2[j] = (c < OUTD) ? f2b(Wl2[k * OUTD + c]) : (u16)0;
        Wrt2[j] = (c < OUTD) ? f2b(Wr2[k * OUTD + c]) : (u16)0;
    }
}

// ======================= CSR build =======================
__global__ void k_hist(const int* __restrict__ dst, int* __restrict__ cnt) {
    int e = blockIdx.x * blockDim.x + threadIdx.x;
    if (e < N_EDGES) atomicAdd(&cnt[dst[e]], 1);
}

__global__ __launch_bounds__(1024) void k_scan(const int* __restrict__ cnt, int* __restrict__ rowptr) {
    __shared__ int part[1024];
    int tid = threadIdx.x;
    const int CH = (N_NODES + 1023) / 1024;   // 49
    int beg = tid * CH;
    int end = beg + CH; if (end > N_NODES) end = N_NODES;
    int s = 0;
    for (int i = beg; i < end && i >= beg; i++) s += cnt[i];
    part[tid] = s;
    __syncthreads();
    for (int off = 1; off < 1024; off <<= 1) {
        int v = (tid >= off) ? part[tid - off] : 0;
        __syncthreads();
        part[tid] += v;
        __syncthreads();
    }
    int run = (tid == 0) ? 0 : part[tid - 1];
    for (int i = beg; i < end && i >= beg; i++) { rowptr[i] = run; run += cnt[i]; }
    if (tid == 1023) rowptr[N_NODES] = run;
}

// epk.x = e*64, epk.y = src index; dstc[j] = dst node
__global__ void k_scatter(const int* __restrict__ src, const int* __restrict__ dst,
                          const int* __restrict__ rowptr, int* __restrict__ cursor,
                          int2* __restrict__ epk, int* __restrict__ dstc) {
    int e = blockIdx.x * blockDim.x + threadIdx.x;
    if (e >= N_EDGES) return;
    int d = dst[e];
    int pos = atomicAdd(&cursor[d], 1);
    int j = rowptr[d] + pos;
    epk[j] = make_int2(e << 6, src[e]);
    dstc[j] = d;
}

// ======= reorder edge features into CSR order (f16, zero-padded to 32):
//         eac[j] = f16(ea[e_j])  — logits kernels then read a coalesced stream =======
__global__ void k_reorder(const int2* __restrict__ epk, const float* __restrict__ ea,
                          u32* __restrict__ eac) {
    int i = blockIdx.x * blockDim.x + threadIdx.x;
    if (i >= N_EDGES * 8) return;
    int j = i >> 3, part = i & 7;
    int e = ((u32)epk[j].x) >> 6;
    if (part < 7) {
        float4 v = *(const float4*)(ea + (size_t)e * EDIM + part * 4);
        *(uint2*)(eac + ((size_t)j << 4) + part * 2) = make_uint2(hpack(v.x, v.y), hpack(v.z, v.w));
    } else {
        *(uint2*)(eac + ((size_t)j << 4) + 14) = make_uint2(0u, 0u);
    }
}

// ======================= partial-sum reducer =======================
__global__ __launch_bounds__(256) void k_sumpart(const float* __restrict__ P, int n, float* __restrict__ S) {
    float s1 = 0.f, s2 = 0.f;
    int stride = gridDim.x * blockDim.x;
    for (int i = blockIdx.x * blockDim.x + threadIdx.x; i < n; i += stride) {
        s1 += P[2 * i]; s2 += P[2 * i + 1];
    }
    #pragma unroll
    for (int off = 32; off; off >>= 1) { s1 += __shfl_xor(s1, off); s2 += __shfl_xor(s2, off); }
    __shared__ float w1[4], w2[4];
    int w = threadIdx.x >> 6;
    if ((threadIdx.x & 63) == 0) { w1[w] = s1; w2[w] = s2; }
    __syncthreads();
    if (threadIdx.x == 0) {
        atomicAdd(S,     w1[0] + w1[1] + w1[2] + w1[3]);
        atomicAdd(S + 1, w2[0] + w2[1] + w2[2] + w2[3]);
    }
}

// ======================= conv1 node transform via MFMA =======================
__global__ __launch_bounds__(256) void k_node1(
    const int* __restrict__ x, const u16* __restrict__ embb,
    const u16* __restrict__ Wlt, const u16* __restrict__ Wrt,
    const float* __restrict__ bl, const float* __restrict__ br,
    u16* __restrict__ xl, u16* __restrict__ xr)
{
    int w = threadIdx.x >> 6, lane = threadIdx.x & 63;
    int c = lane & 15, kg = lane >> 4;
    s8v bL[4][2], bR[4][2];
    float blv[4], brv[4];
    #pragma unroll
    for (int ct = 0; ct < 4; ct++) {
        int col = (w << 6) + (ct << 4) + c;
        #pragma unroll
        for (int ks = 0; ks < 2; ks++) {
            bL[ct][ks] = *(const s8v*)(Wlt + ((u32)col << 6) + (ks << 5) + (kg << 3));
            bR[ct][ks] = *(const s8v*)(Wrt + ((u32)col << 6) + (ks << 5) + (kg << 3));
        }
        blv[ct] = bl[col];
        brv[ct] = br[col];
    }
    const int NTILES = N_NODES / 16;   // 3125
    for (int t = blockIdx.x; t < NTILES; t += gridDim.x) {
        int nb = t << 4;
        int xi = x[nb + c];
        const u16* er = embb + ((u32)xi << 6);
        s8v a0 = *(const s8v*)(er + (kg << 3));
        s8v a1 = *(const s8v*)(er + 32 + (kg << 3));
        #pragma unroll
        for (int ct = 0; ct < 4; ct++) {
            int col = (w << 6) + (ct << 4) + c;
            f4 accL = {blv[ct], blv[ct], blv[ct], blv[ct]};
            f4 accR = {brv[ct], brv[ct], brv[ct], brv[ct]};
            accL = __builtin_amdgcn_mfma_f32_16x16x32_bf16(a0, bL[ct][0], accL, 0, 0, 0);
            accL = __builtin_amdgcn_mfma_f32_16x16x32_bf16(a1, bL[ct][1], accL, 0, 0, 0);
            accR = __builtin_amdgcn_mfma_f32_16x16x32_bf16(a0, bR[ct][0], accR, 0, 0, 0);
            accR = __builtin_amdgcn_mfma_f32_16x16x32_bf16(a1, bR[ct][1], accR, 0, 0, 0);
            #pragma unroll
            for (int i = 0; i < 4; i++) {
                int node = nb + (kg << 2) + i;
                xl[((size_t)node << 8) + col] = f2b(accL[i]);
                xr[((size_t)node << 8) + col] = f2b(accR[i]);
            }
        }
    }
}

// ======================= conv1 edge logits via MFMA (round-6 structure, eac stream) ======
__global__ __launch_bounds__(256) void k_logits1(
    const int2* __restrict__ epk, const int* __restrict__ dstc,
    const u32* __restrict__ eac, const u16* __restrict__ xl, const u16* __restrict__ xr,
    const u32* __restrict__ Weh, const float* __restrict__ atts,
    float* __restrict__ Lg)
{
    int lane = threadIdx.x & 63;
    int er = lane & 15, grp = lane >> 4;
    hf8 wA[16];
    #pragma unroll
    for (int ct = 0; ct < 16; ct++) {
        uint4 q;
        q.x = Weh[(grp * 4 + 0) * 256 + ct * 16 + er];
        q.y = Weh[(grp * 4 + 1) * 256 + ct * 16 + er];
        q.z = Weh[(grp * 4 + 2) * 256 + ct * 16 + er];
        q.w = Weh[(grp * 4 + 3) * 256 + ct * 16 + er];
        wA[ct] = __builtin_bit_cast(hf8, q);
    }
    int wid = blockIdx.x * 4 + (threadIdx.x >> 6);
    int nw = gridDim.x * 4;
    const char* eab = (const char*)eac;
    const f4 zero = {0.f, 0.f, 0.f, 0.f};
    for (int t = wid; t < N_EDGES / 16; t += nw) {
        int j = t * 16 + er;
        int2 p = epk[j];
        int d = dstc[j];
        hf8 bfrag = *(const hf8*)(eab + ((size_t)j << 6) + (grp << 4));   // CSR-ordered stream
        const u16* xlp = xl + ((u32)p.y << 8);
        const u16* xrp = xr + ((u32)d << 8);
        float part0 = 0.f, part1 = 0.f, part2 = 0.f, part3 = 0.f;
        #pragma unroll
        for (int ct = 0; ct < 16; ct++) {
            int c0 = ct * 16 + grp * 4;
            f4 z = __builtin_amdgcn_mfma_f32_16x16x32_f16(wA[ct], bfrag, zero, 0, 0, 0);
            uint2 ql = *(const uint2*)(xlp + c0);
            uint2 qr = *(const uint2*)(xrp + c0);
            float4 av = *(const float4*)(atts + c0);
            float z0 = z[0] + __uint_as_float(ql.x << 16)        + __uint_as_float(qr.x << 16);
            float z1 = z[1] + __uint_as_float(ql.x & 0xFFFF0000u) + __uint_as_float(qr.x & 0xFFFF0000u);
            float z2 = z[2] + __uint_as_float(ql.y << 16)        + __uint_as_float(qr.y << 16);
            float z3 = z[3] + __uint_as_float(ql.y & 0xFFFF0000u) + __uint_as_float(qr.y & 0xFFFF0000u);
            float s = av.x * fmaxf(z0, NEG * z0) + av.y * fmaxf(z1, NEG * z1)
                    + av.z * fmaxf(z2, NEG * z2) + av.w * fmaxf(z3, NEG * z3);
            if      (ct < 4)  part0 += s;
            else if (ct < 8)  part1 += s;
            else if (ct < 12) part2 += s;
            else              part3 += s;
        }
        part0 += __shfl_xor(part0, 16); part0 += __shfl_xor(part0, 32);
        part1 += __shfl_xor(part1, 16); part1 += __shfl_xor(part1, 32);
        part2 += __shfl_xor(part2, 16); part2 += __shfl_xor(part2, 32);
        part3 += __shfl_xor(part3, 16); part3 += __shfl_xor(part3, 32);
        float v01 = (grp & 1) ? part1 : part0;
        float v23 = (grp & 1) ? part3 : part2;
        float v = (grp & 2) ? v23 : v01;
        Lg[((size_t)j << 2) + grp] = v;   // [j][h] layout, coalesced 256B/wave
    }
}

// ======================= conv1 fused (light): softmax + aggregate only ===========
__global__ __launch_bounds__(256) void k_fused1(
    const int* __restrict__ rowptr, const int2* __restrict__ epk,
    const float* __restrict__ Lg, const u16* __restrict__ xl,
    const float* __restrict__ bias, u16* __restrict__ out, float* __restrict__ Spart)
{
    int node = blockIdx.x;
    int tid = threadIdx.x;          // global column 0..255
    int h = tid >> 6, lane = tid & 63;
    int beg = rowptr[node], end = rowptr[node + 1];
    float acc = 0.f, dtot = 0.f;
    int j = beg;
    for (; j + 3 < end; j += 4) {
        int2 pA = epk[j], pB = epk[j + 1], pC = epk[j + 2], pD = epk[j + 3];
        float g1 = Lg[((size_t)j << 2) + h];
        float g2 = Lg[((size_t)j << 2) + 4 + h];
        float g3 = Lg[((size_t)j << 2) + 8 + h];
        float g4 = Lg[((size_t)j << 2) + 12 + h];
        float xA = b2f(xl[((u32)pA.y << 8) + tid]);
        float xB = b2f(xl[((u32)pB.y << 8) + tid]);
        float xC = b2f(xl[((u32)pC.y << 8) + tid]);
        float xD = b2f(xl[((u32)pD.y << 8) + tid]);
        float p1 = exp2f(g1), p2 = exp2f(g2), p3 = exp2f(g3), p4 = exp2f(g4);
        acc  += (p1 * xA + p2 * xB) + (p3 * xC + p4 * xD);
        dtot += (p1 + p2) + (p3 + p4);
    }
    for (; j < end; j++) {
        int2 p = epk[j];
        float pe = exp2f(Lg[((size_t)j << 2) + h]);
        float xA = b2f(xl[((u32)p.y << 8) + tid]);
        acc += pe * xA; dtot += pe;
    }
    float o = ((end > beg) ? acc / (dtot + EPS_SM) : 0.f) + bias[tid];
    out[((size_t)node << 8) + tid] = f2b(o);
    float s1 = o, s2 = o * o;
    #pragma unroll
    for (int off = 32; off; off >>= 1) { s1 += __shfl_xor(s1, off); s2 += __shfl_xor(s2, off); }
    __shared__ float ls1[4], ls2[4];
    if (lane == 0) { ls1[h] = s1; ls2[h] = s2; }
    __syncthreads();
    if (tid == 0) {
        Spart[(size_t)node * 2]     = ls1[0] + ls1[1] + ls1[2] + ls1[3];
        Spart[(size_t)node * 2 + 1] = ls2[0] + ls2[1] + ls2[2] + ls2[3];
    }
}

// ======================= LayerNorm apply (+ReLU) in-place on bf16 =======================
__global__ void k_ln_apply_relu_b(
    u16* v, const float* __restrict__ w, const float* __restrict__ b,
    const float* __restrict__ S, int M, int C)
{
    int i = blockIdx.x * blockDim.x + threadIdx.x;
    if (i >= M) return;
    float mu = S[0] / (float)M;
    float var = S[1] / (float)M - mu * mu;
    float inv = 1.f / (sqrtf(fmaxf(var, 0.f)) + EPS_LN);
    int c = i % C;
    float y = (b2f(v[i]) - mu) * inv * w[c] + b[c];
    v[i] = f2b(fmaxf(y, 0.f));
}

__global__ void k_ln_out(
    const float* __restrict__ v, const float* __restrict__ w, const float* __restrict__ b,
    const float* __restrict__ S, int M, int C, float* __restrict__ out)
{
    int i = blockIdx.x * blockDim.x + threadIdx.x;
    if (i >= M) return;
    float mu = S[0] / (float)M;
    float var = S[1] / (float)M - mu * mu;
    float inv = 1.f / (sqrtf(fmaxf(var, 0.f)) + EPS_LN);
    int c = i % C;
    out[i] = (v[i] - mu) * inv * w[c] + b[c];
}

// ======================= conv2 node transform via MFMA (bf16 rows padded to 64) =========
__global__ __launch_bounds__(256) void k_node2(
    const u16* __restrict__ h, const u16* __restrict__ Wlt, const u16* __restrict__ Wrt,
    const float* __restrict__ bl, const float* __restrict__ br,
    u16* __restrict__ xlb, u16* __restrict__ xrb)
{
    int w = threadIdx.x >> 6, lane = threadIdx.x & 63;
    int c = lane & 15, kg = lane >> 4;
    int col = (w << 4) + c;                       // 0..63
    s8v bL[8], bR[8];
    #pragma unroll
    for (int ks = 0; ks < 8; ks++) {
        bL[ks] = *(const s8v*)(Wlt + ((u32)col << 8) + (ks << 5) + (kg << 3));
        bR[ks] = *(const s8v*)(Wrt + ((u32)col << 8) + (ks << 5) + (kg << 3));
    }
    float blv = (col < OUTD) ? bl[col] : 0.f;
    float brv = (col < OUTD) ? br[col] : 0.f;
    const int NTILES = N_NODES / 16;   // 3125
    for (int t = blockIdx.x; t < NTILES; t += gridDim.x) {
        int nb = t << 4;
        const u16* hrow = h + ((size_t)(nb + c) << 8) + (kg << 3);
        f4 accL = {blv, blv, blv, blv};
        f4 accR = {brv, brv, brv, brv};
        #pragma unroll
        for (int ks = 0; ks < 8; ks++) {
            s8v a = *(const s8v*)(hrow + (ks << 5));
            accL = __builtin_amdgcn_mfma_f32_16x16x32_bf16(a, bL[ks], accL, 0, 0, 0);
            accR = __builtin_amdgcn_mfma_f32_16x16x32_bf16(a, bR[ks], accR, 0, 0, 0);
        }
        #pragma unroll
        for (int i = 0; i < 4; i++) {
            int node = nb + (kg << 2) + i;
            xlb[((u32)node << 6) + col] = f2b(accL[i]);
            xrb[((u32)node << 6) + col] = f2b(accR[i]);
        }
    }
}

// ======================= conv2 edge logits via MFMA (1 head, eac stream) ==========
__global__ __launch_bounds__(256) void k_logits2(
    const int2* __restrict__ epk, const int* __restrict__ dstc,
    const u32* __restrict__ eac, const u16* __restrict__ xlb, const u16* __restrict__ xrb,
    const u32* __restrict__ Weh, const float* __restrict__ atts,
    float* __restrict__ Lg2)
{
    int lane = threadIdx.x & 63;
    int er = lane & 15, grp = lane >> 4;
    hf8 wA[4];
    #pragma unroll
    for (int ct = 0; ct < 4; ct++) {
        uint4 q;
        q.x = Weh[(grp * 4 + 0) * 64 + ct * 16 + er];
        q.y = Weh[(grp * 4 + 1) * 64 + ct * 16 + er];
        q.z = Weh[(grp * 4 + 2) * 64 + ct * 16 + er];
        q.w = Weh[(grp * 4 + 3) * 64 + ct * 16 + er];
        wA[ct] = __builtin_bit_cast(hf8, q);
    }
    int wid = blockIdx.x * 4 + (threadIdx.x >> 6);
    int nw = gridDim.x * 4;
    const char* eab = (const char*)eac;
    const f4 zero = {0.f, 0.f, 0.f, 0.f};
    for (int t = wid; t < N_EDGES / 16; t += nw) {
        int j = t * 16 + er;
        int2 p = epk[j];
        int d = dstc[j];
        hf8 bfrag = *(const hf8*)(eab + ((size_t)j << 6) + (grp << 4));   // CSR-ordered stream
        const u16* xlp = xlb + ((u32)p.y << 6);
        const u16* xrp = xrb + ((u32)d << 6);
        float tot = 0.f;
        #pragma unroll
        for (int ct = 0; ct < 4; ct++) {
            int c0 = ct * 16 + grp * 4;
            f4 z = __builtin_amdgcn_mfma_f32_16x16x32_f16(wA[ct], bfrag, zero, 0, 0, 0);
            uint2 ql = *(const uint2*)(xlp + c0);
            uint2 qr = *(const uint2*)(xrp + c0);
            float4 av = *(const float4*)(atts + c0);
            float z0 = z[0] + __uint_as_float(ql.x << 16)        + __uint_as_float(qr.x << 16);
            float z1 = z[1] + __uint_as_float(ql.x & 0xFFFF0000u) + __uint_as_float(qr.x & 0xFFFF0000u);
            float z2 = z[2] + __uint_as_float(ql.y << 16)        + __uint_as_float(qr.y << 16);
            float z3 = z[3] + __uint_as_float(ql.y & 0xFFFF0000u) + __uint_as_float(qr.y & 0xFFFF0000u);
            tot += av.x * fmaxf(z0, NEG * z0) + av.y * fmaxf(z1, NEG * z1)
                 + av.z * fmaxf(z2, NEG * z2) + av.w * fmaxf(z3, NEG * z3);
        }
        tot += __shfl_xor(tot, 16);
        tot += __shfl_xor(tot, 32);
        if (lane < 16) Lg2[j] = tot;   // 64B coalesced per tile
    }
}

// ======================= conv2 fused (light): softmax + aggregate only ===========
__global__ __launch_bounds__(256) void k_fused2(
    const int* __restrict__ rowptr, const int2* __restrict__ epk,
    const float* __restrict__ Lg2, const u16* __restrict__ xlb,
    const float* __restrict__ bias, float* __restrict__ out, float* __restrict__ Spart)
{
    int w = threadIdx.x >> 6, lane = threadIdx.x & 63;
    int node = blockIdx.x * 4 + w;
    bool col = lane < OUTD;
    int beg = rowptr[node], end = rowptr[node + 1];
    float acc = 0.f, dtot = 0.f;
    int j = beg;
    for (; j + 3 < end; j += 4) {
        int2 p0 = epk[j], p1 = epk[j + 1], p2 = epk[j + 2], p3 = epk[j + 3];
        float g0 = Lg2[j], g1 = Lg2[j + 1], g2 = Lg2[j + 2], g3 = Lg2[j + 3];
        float x0 = b2f(xlb[((u32)p0.y << 6) + lane]);
        float x1 = b2f(xlb[((u32)p1.y << 6) + lane]);
        float x2 = b2f(xlb[((u32)p2.y << 6) + lane]);
        float x3 = b2f(xlb[((u32)p3.y << 6) + lane]);
        float e0 = exp2f(g0), e1 = exp2f(g1), e2 = exp2f(g2), e3 = exp2f(g3);
        acc  += (e0 * x0 + e1 * x1) + (e2 * x2 + e3 * x3);
        dtot += (e0 + e1) + (e2 + e3);
    }
    for (; j < end; j++) {
        int2 p = epk[j];
        float e = exp2f(Lg2[j]);
        float xv = b2f(xlb[((u32)p.y << 6) + lane]);
        acc += e * xv; dtot += e;
    }
    float s1 = 0.f, s2 = 0.f;
    if (col) {
        float o = ((end > beg) ? acc / (dtot + EPS_SM) : 0.f) + bias[lane];
        out[(u32)node * OUTD + lane] = o;
        s1 = o; s2 = o * o;
    }
    #pragma unroll
    for (int off = 32; off; off >>= 1) { s1 += __shfl_xor(s1, off); s2 += __shfl_xor(s2, off); }
    __shared__ float ls1[4], ls2[4];
    if (lane == 0) { ls1[w] = s1; ls2[w] = s2; }
    __syncthreads();
    if (threadIdx.x == 0) {
        Spart[(size_t)blockIdx.x * 2]     = ls1[0] + ls1[1] + ls1[2] + ls1[3];
        Spart[(size_t)blockIdx.x * 2 + 1] = ls2[0] + ls2[1] + ls2[2] + ls2[3];
    }
}

extern "C" void kernel_launch(void* const* d_in, const int* in_sizes, int n_in,
                              void* d_out, int out_size, void* d_ws, size_t ws_size,
                              hipStream_t stream)
{
    const int*   x    = (const int*)d_in[0];
    const int*   ei   = (const int*)d_in[1];
    const int*   srcA = ei;
    const int*   dstA = ei + N_EDGES;
    const float* ea   = (const float*)d_in[2];
    const float* emb  = (const float*)d_in[3];
    const float* Wl1  = (const float*)d_in[4];
    const float* bl1  = (const float*)d_in[5];
    const float* Wr1  = (const float*)d_in[6];
    const float* br1  = (const float*)d_in[7];
    const float* We1  = (const float*)d_in[8];
    const float* att1 = (const float*)d_in[9];
    const float* bias1= (const float*)d_in[10];
    const float* ln1w = (const float*)d_in[11];
    const float* ln1b = (const float*)d_in[12];
    const float* Wl2  = (const float*)d_in[13];
    const float* bl2  = (const float*)d_in[14];
    const float* Wr2  = (const float*)d_in[15];
    const float* br2  = (const float*)d_in[16];
    const float* We2  = (const float*)d_in[17];
    const float* att2 = (const float*)d_in[18];
    const float* bias2= (const float*)d_in[19];
    const float* ln2w = (const float*)d_in[20];
    const float* ln2b = (const float*)d_in[21];

    // workspace layout (float-slot offsets); peak 31,000,000 slots = 124.0 MB
    float* W = (float*)d_ws;
    u16*   xl1b    = (u16*)W;                      // [0, 6.4M)
    u16*   xr1b    = (u16*)(W + 6400000);          // [6.4M, 12.8M)
    u16*   out1b   = (u16*)(W + 12800000);         // [12.8M, 19.2M)  bf16, h1 in place
    u32*   eac     = (u32*)(W + 19200000);         // E*16 u32 [19.2M, 27.2M)  CSR-ordered f16 rows
    int2*  epk     = (int2*)(W + 27200000);        // [27.2M, 28.2M)
    int*   rowptr  = (int*)(W + 28200000);         // 50,001 ints, 60k slots
    int*   cnt     = (int*)(W + 28260000);         // N
    int*   cursor  = (int*)(W + 28310000);         // N
    float* Spart   = W + 28360000;                 // 2*N
    float* S       = W + 28460000;                 // 4
    u32*   Weh1    = (u32*)(W + 28470000);         // 16*256 = 4096 (k2>=14 zero)
    u32*   Weh2    = (u32*)(W + 28480000);         // 16*64  = 1024 (padded)
    float* atts1   = W + 28481100;                 // 256
    float* atts2   = W + 28481600;                 // 64
    int*   dstc    = (int*)(W + 28482000);         // E ints = 500k slots [28.482M, 28.982M)
    u16*   Wlt2    = (u16*)(W + 28982000);         // 64*256 u16 = 8192 slots
    u16*   Wrt2    = (u16*)(W + 28991000);         // 64*256 u16 = 8192 slots
    float* Lg      = W + 29000000;                 // E*4 f32 [29M, 31M)  (conv1, written by logits1)
    // pre-conv1 transients (dead before logits1 writes Lg; parked inside Lg region):
    u16*   embb    = (u16*)(W + 29000000);         // N*64 u16 = 1.6M slots [29.0M, 30.6M)
    u16*   Wlt1    = (u16*)(W + 30600000);         // 256*64 u16 = 8192 slots
    u16*   Wrt1    = (u16*)(W + 30610000);         // 256*64 u16 = 8192 slots
    // conv2 reuse (liveness: xl1b/xr1b dead after fused1; Lg dead after fused1):
    u16*   xl2b    = (u16*)W;                      // N*64 u16 [0, 1.6M)
    u16*   xr2b    = (u16*)(W + 1600000);          // N*64 u16 [1.6M, 3.2M)
    float* out2    = W + 3200000;                  // N*50 f32 [3.2M, 5.7M)
    float* Lg2     = W + 29000000;                 // E f32 (reuses Lg region)
    u16*   h1      = out1b;

    // init + W transpose pack + CSR build + CSR-ordered edge-feature pack
    k_init<<<(N_NODES * 64 + 255) / 256, 256, 0, stream>>>(cnt, cursor, S,
                                                           We1, We2, Weh1, Weh2,
                                                           att1, att2, atts1, atts2,
                                                           emb, embb);
    k_packw<<<128, 256, 0, stream>>>(Wl1, Wr1, Wlt1, Wrt1, Wl2, Wr2, Wlt2, Wrt2);
    k_hist<<<(N_EDGES + 255) / 256, 256, 0, stream>>>(dstA, cnt);
    k_scan<<<1, 1024, 0, stream>>>(cnt, rowptr);
    k_scatter<<<(N_EDGES + 255) / 256, 256, 0, stream>>>(srcA, dstA, rowptr, cursor, epk, dstc);
    k_reorder<<<(N_EDGES * 8 + 255) / 256, 256, 0, stream>>>(epk, ea, eac);

    // conv1
    k_node1<<<1024, 256, 0, stream>>>(x, embb, Wlt1, Wrt1, bl1, br1, xl1b, xr1b);
    k_logits1<<<1024, 256, 0, stream>>>(epk, dstc, eac, xl1b, xr1b, Weh1, atts1, Lg);
    k_fused1<<<N_NODES, 256, 0, stream>>>(rowptr, epk, Lg, xl1b, bias1, out1b, Spart);
    k_sumpart<<<32, 256, 0, stream>>>(Spart, N_NODES, S);
    k_ln_apply_relu_b<<<(N_NODES * F1 + 255) / 256, 256, 0, stream>>>(h1, ln1w, ln1b, S, N_NODES * F1, F1);

    // conv2
    k_node2<<<1024, 256, 0, stream>>>(h1, Wlt2, Wrt2, bl2, br2, xl2b, xr2b);
    k_logits2<<<1024, 256, 0, stream>>>(epk, dstc, eac, xl2b, xr2b, Weh2, atts2, Lg2);
    k_fused2<<<N_NODES / 4, 256, 0, stream>>>(rowptr, epk, Lg2, xl2b, bias2, out2, Spart);
    k_sumpart<<<32, 256, 0, stream>>>(Spart, N_NODES / 4, S + 2);
    k_ln_out<<<(N_NODES * OUTD + 255) / 256, 256, 0, stream>>>(out2, ln2w, ln2b, S + 2, N_NODES * OUTD, OUTD, (float*)d_out);
}

// Round 10
// 590.288 us; speedup vs baseline: 1.1387x; 1.0429x over previous
//
#include <hip/hip_runtime.h>

#define N_NODES 50000
#define N_EDGES 500000
#define EMB 50
#define HID 64
#define OUTD 50
#define EDIM 28
#define HEADS 4
#define F1 256              // HEADS*HID
#define NEG 0.2f
#define EPS_SM 1e-16f
#define EPS_LN 1e-5f
#define LOG2E 1.4426950408889634f

typedef unsigned short u16;
typedef unsigned int u32;
typedef _Float16 hf;
typedef hf h2 __attribute__((ext_vector_type(2)));
typedef hf hf8 __attribute__((ext_vector_type(8)));
typedef float f4 __attribute__((ext_vector_type(4)));
typedef short s8v __attribute__((ext_vector_type(8)));   // 8 bf16 (4 VGPRs)

__device__ __forceinline__ float b2f(u16 u) { return __uint_as_float(((u32)u) << 16); }
__device__ __forceinline__ u16 f2b(float f) {
    u32 u = __float_as_uint(f);
    u32 r = (u + 0x7FFFu + ((u >> 16) & 1u)) >> 16;
    return (u16)r;
}
__device__ __forceinline__ h2 uq(u32 u) { return __builtin_bit_cast(h2, u); }
__device__ __forceinline__ u32 hpack(float a, float b) {
    h2 p = {(hf)a, (hf)b};
    return __builtin_bit_cast(u32, p);
}
__device__ __forceinline__ float lrelu(float x) { return x > 0.f ? x : NEG * x; }

// ======= init: zero cnt/cursor/S + ea->f16 rows (zero-padded to 32) + We->f16 packed
//         + emb->bf16 rows padded to 64 + att*log2e =======
__global__ void k_init(int* __restrict__ cnt, int* __restrict__ cursor, float* __restrict__ S,
                       const float* __restrict__ a, u32* __restrict__ o,
                       const float* __restrict__ We1, const float* __restrict__ We2,
                       u32* __restrict__ Weh1, u32* __restrict__ Weh2,
                       const float* __restrict__ att1, const float* __restrict__ att2,
                       float* __restrict__ atts1, float* __restrict__ atts2,
                       const float* __restrict__ emb, u16* __restrict__ embb) {
    int i = blockIdx.x * blockDim.x + threadIdx.x;
    if (i < N_NODES) cnt[i] = 0;
    else if (i < 2 * N_NODES) cursor[i - N_NODES] = 0;
    else if (i < 2 * N_NODES + 4) S[i - 2 * N_NODES] = 0.f;
    if (i < F1 * 16) {               // Weh1[k2*256+c], k2 in [0,16), zero-padded k2>=14
        int k2 = i >> 8, c = i & 255;
        Weh1[i] = (k2 < 14) ? hpack(We1[(2 * k2) * F1 + c], We1[(2 * k2 + 1) * F1 + c]) : 0u;
    } else if (i < F1 * 16 + 64 * 16) {  // Weh2[k2*64+c], k2>=14 or c>=OUTD zero-padded
        int j = i - F1 * 16;
        int k2 = j >> 6, c = j & 63;
        Weh2[j] = (k2 < 14 && c < OUTD) ? hpack(We2[(2 * k2) * OUTD + c], We2[(2 * k2 + 1) * OUTD + c]) : 0u;
    } else {
        int ja = i - (F1 * 16 + 64 * 16);
        if (ja < 256) atts1[ja] = att1[ja] * LOG2E;
        else if (ja < 320) {
            int c = ja - 256;
            atts2[c] = (c < OUTD) ? att2[c] * LOG2E : 0.f;
        }
    }
    if (i < N_NODES * 64) {          // embb[node][64] bf16, k>=EMB zero
        int node = i >> 6, k = i & 63;
        embb[i] = (k < EMB) ? f2b(emb[(size_t)node * EMB + k]) : (u16)0;
    }
    if (i < N_EDGES * 8) {           // 8 parts/row: parts 0..6 pack ea, part 7 zero-pads k=28..31
        int e = i >> 3, part = i & 7;
        if (part < 7) {
            float4 v = *(const float4*)(a + (size_t)e * EDIM + part * 4);
            *(uint2*)(o + (size_t)e * 16 + part * 2) = make_uint2(hpack(v.x, v.y), hpack(v.z, v.w));
        } else {
            *(uint2*)(o + (size_t)e * 16 + 14) = make_uint2(0u, 0u);
        }
    }
}

// ======= pack W transposed bf16 for MFMA node kernels =======
__global__ void k_packw(const float* __restrict__ Wl1, const float* __restrict__ Wr1,
                        u16* __restrict__ Wlt1, u16* __restrict__ Wrt1,
                        const float* __restrict__ Wl2, const float* __restrict__ Wr2,
                        u16* __restrict__ Wlt2, u16* __restrict__ Wrt2) {
    int i = blockIdx.x * blockDim.x + threadIdx.x;
    if (i < 256 * 64) {
        int c = i >> 6, k = i & 63;
        Wlt1[i] = (k < EMB) ? f2b(Wl1[k * F1 + c]) : (u16)0;
        Wrt1[i] = (k < EMB) ? f2b(Wr1[k * F1 + c]) : (u16)0;
    } else if (i < 2 * 256 * 64) {
        int j = i - 256 * 64;
        int c = j >> 8, k = j & 255;
        Wlt2[j] = (c < OUTD) ? f2b(Wl2[k * OUTD + c]) : (u16)0;
        Wrt2[j] = (c < OUTD) ? f2b(Wr2[k * OUTD + c]) : (u16)0;
    }
}

// ======================= CSR build =======================
__global__ void k_hist(const int* __restrict__ dst, int* __restrict__ cnt) {
    int e = blockIdx.x * blockDim.x + threadIdx.x;
    if (e < N_EDGES) atomicAdd(&cnt[dst[e]], 1);
}

__global__ __launch_bounds__(1024) void k_scan(const int* __restrict__ cnt, int* __restrict__ rowptr) {
    __shared__ int part[1024];
    int tid = threadIdx.x;
    const int CH = (N_NODES + 1023) / 1024;   // 49
    int beg = tid * CH;
    int end = beg + CH; if (end > N_NODES) end = N_NODES;
    int s = 0;
    for (int i = beg; i < end && i >= beg; i++) s += cnt[i];
    part[tid] = s;
    __syncthreads();
    for (int off = 1; off < 1024; off <<= 1) {
        int v = (tid >= off) ? part[tid - off] : 0;
        __syncthreads();
        part[tid] += v;
        __syncthreads();
    }
    int run = (tid == 0) ? 0 : part[tid - 1];
    for (int i = beg; i < end && i >= beg; i++) { rowptr[i] = run; run += cnt[i]; }
    if (tid == 1023) rowptr[N_NODES] = run;
}

// epk.x = e*64 (byte offset into eah rows), epk.y = src index; dstc[j] = dst node
__global__ void k_scatter(const int* __restrict__ src, const int* __restrict__ dst,
                          const int* __restrict__ rowptr, int* __restrict__ cursor,
                          int2* __restrict__ epk, int* __restrict__ dstc) {
    int e = blockIdx.x * blockDim.x + threadIdx.x;
    if (e >= N_EDGES) return;
    int d = dst[e];
    int pos = atomicAdd(&cursor[d], 1);
    int j = rowptr[d] + pos;
    epk[j] = make_int2(e << 6, src[e]);
    dstc[j] = d;
}

// ======================= partial-sum reducer =======================
__global__ __launch_bounds__(256) void k_sumpart(const float* __restrict__ P, int n, float* __restrict__ S) {
    float s1 = 0.f, s2 = 0.f;
    int stride = gridDim.x * blockDim.x;
    for (int i = blockIdx.x * blockDim.x + threadIdx.x; i < n; i += stride) {
        s1 += P[2 * i]; s2 += P[2 * i + 1];
    }
    #pragma unroll
    for (int off = 32; off; off >>= 1) { s1 += __shfl_xor(s1, off); s2 += __shfl_xor(s2, off); }
    __shared__ float w1[4], w2[4];
    int w = threadIdx.x >> 6;
    if ((threadIdx.x & 63) == 0) { w1[w] = s1; w2[w] = s2; }
    __syncthreads();
    if (threadIdx.x == 0) {
        atomicAdd(S,     w1[0] + w1[1] + w1[2] + w1[3]);
        atomicAdd(S + 1, w2[0] + w2[1] + w2[2] + w2[3]);
    }
}

// ======================= conv1 node transform via MFMA =======================
__global__ __launch_bounds__(256) void k_node1(
    const int* __restrict__ x, const u16* __restrict__ embb,
    const u16* __restrict__ Wlt, const u16* __restrict__ Wrt,
    const float* __restrict__ bl, const float* __restrict__ br,
    u16* __restrict__ xl, u16* __restrict__ xr)
{
    int w = threadIdx.x >> 6, lane = threadIdx.x & 63;
    int c = lane & 15, kg = lane >> 4;
    s8v bL[4][2], bR[4][2];
    float blv[4], brv[4];
    #pragma unroll
    for (int ct = 0; ct < 4; ct++) {
        int col = (w << 6) + (ct << 4) + c;
        #pragma unroll
        for (int ks = 0; ks < 2; ks++) {
            bL[ct][ks] = *(const s8v*)(Wlt + ((u32)col << 6) + (ks << 5) + (kg << 3));
            bR[ct][ks] = *(const s8v*)(Wrt + ((u32)col << 6) + (ks << 5) + (kg << 3));
        }
        blv[ct] = bl[col];
        brv[ct] = br[col];
    }
    const int NTILES = N_NODES / 16;   // 3125
    for (int t = blockIdx.x; t < NTILES; t += gridDim.x) {
        int nb = t << 4;
        int xi = x[nb + c];
        const u16* er = embb + ((u32)xi << 6);
        s8v a0 = *(const s8v*)(er + (kg << 3));
        s8v a1 = *(const s8v*)(er + 32 + (kg << 3));
        #pragma unroll
        for (int ct = 0; ct < 4; ct++) {
            int col = (w << 6) + (ct << 4) + c;
            f4 accL = {blv[ct], blv[ct], blv[ct], blv[ct]};
            f4 accR = {brv[ct], brv[ct], brv[ct], brv[ct]};
            accL = __builtin_amdgcn_mfma_f32_16x16x32_bf16(a0, bL[ct][0], accL, 0, 0, 0);
            accL = __builtin_amdgcn_mfma_f32_16x16x32_bf16(a1, bL[ct][1], accL, 0, 0, 0);
            accR = __builtin_amdgcn_mfma_f32_16x16x32_bf16(a0, bR[ct][0], accR, 0, 0, 0);
            accR = __builtin_amdgcn_mfma_f32_16x16x32_bf16(a1, bR[ct][1], accR, 0, 0, 0);
            #pragma unroll
            for (int i = 0; i < 4; i++) {
                int node = nb + (kg << 2) + i;
                xl[((size_t)node << 8) + col] = f2b(accL[i]);
                xr[((size_t)node << 8) + col] = f2b(accR[i]);
            }
        }
    }
}

// ======================= conv1 edge logits via MFMA (index-prefetch pipeline) ============
// One wave computes the 4 head-logits for 16 CSR-consecutive edges. Next iteration's
// epk/dstc are prefetched so row gathers issue immediately at iteration start.
__global__ __launch_bounds__(256) void k_logits1(
    const int2* __restrict__ epk, const int* __restrict__ dstc,
    const u32* __restrict__ eah, const u16* __restrict__ xl, const u16* __restrict__ xr,
    const u32* __restrict__ Weh, const float* __restrict__ atts,
    float* __restrict__ Lg)
{
    int lane = threadIdx.x & 63;
    int er = lane & 15, grp = lane >> 4;
    hf8 wA[16];
    #pragma unroll
    for (int ct = 0; ct < 16; ct++) {
        uint4 q;
        q.x = Weh[(grp * 4 + 0) * 256 + ct * 16 + er];
        q.y = Weh[(grp * 4 + 1) * 256 + ct * 16 + er];
        q.z = Weh[(grp * 4 + 2) * 256 + ct * 16 + er];
        q.w = Weh[(grp * 4 + 3) * 256 + ct * 16 + er];
        wA[ct] = __builtin_bit_cast(hf8, q);
    }
    int wid = blockIdx.x * 4 + (threadIdx.x >> 6);
    int nw = gridDim.x * 4;
    const int NT = N_EDGES / 16;
    const char* eab = (const char*)eah;
    const f4 zero = {0.f, 0.f, 0.f, 0.f};
    if (wid >= NT) return;
    int2 p = epk[wid * 16 + er];
    int d = dstc[wid * 16 + er];
    for (int t = wid; t < NT; t += nw) {
        int tn = t + nw;
        int2 pn; int dn;
        if (tn < NT) { pn = epk[tn * 16 + er]; dn = dstc[tn * 16 + er]; }
        int j = t * 16 + er;
        hf8 bfrag = *(const hf8*)(eab + (u32)p.x + (grp << 4));
        const u16* xlp = xl + ((u32)p.y << 8);
        const u16* xrp = xr + ((u32)d << 8);
        float part0 = 0.f, part1 = 0.f, part2 = 0.f, part3 = 0.f;
        #pragma unroll
        for (int ct = 0; ct < 16; ct++) {
            int c0 = ct * 16 + grp * 4;
            f4 z = __builtin_amdgcn_mfma_f32_16x16x32_f16(wA[ct], bfrag, zero, 0, 0, 0);
            uint2 ql = *(const uint2*)(xlp + c0);
            uint2 qr = *(const uint2*)(xrp + c0);
            float4 av = *(const float4*)(atts + c0);
            float z0 = z[0] + __uint_as_float(ql.x << 16)        + __uint_as_float(qr.x << 16);
            float z1 = z[1] + __uint_as_float(ql.x & 0xFFFF0000u) + __uint_as_float(qr.x & 0xFFFF0000u);
            float z2 = z[2] + __uint_as_float(ql.y << 16)        + __uint_as_float(qr.y << 16);
            float z3 = z[3] + __uint_as_float(ql.y & 0xFFFF0000u) + __uint_as_float(qr.y & 0xFFFF0000u);
            float s = av.x * fmaxf(z0, NEG * z0) + av.y * fmaxf(z1, NEG * z1)
                    + av.z * fmaxf(z2, NEG * z2) + av.w * fmaxf(z3, NEG * z3);
            if      (ct < 4)  part0 += s;
            else if (ct < 8)  part1 += s;
            else if (ct < 12) part2 += s;
            else              part3 += s;
        }
        part0 += __shfl_xor(part0, 16); part0 += __shfl_xor(part0, 32);
        part1 += __shfl_xor(part1, 16); part1 += __shfl_xor(part1, 32);
        part2 += __shfl_xor(part2, 16); part2 += __shfl_xor(part2, 32);
        part3 += __shfl_xor(part3, 16); part3 += __shfl_xor(part3, 32);
        float v01 = (grp & 1) ? part1 : part0;
        float v23 = (grp & 1) ? part3 : part2;
        float v = (grp & 2) ? v23 : v01;
        Lg[((size_t)j << 2) + grp] = v;   // [j][h] layout, coalesced 256B/wave
        p = pn; d = dn;
    }
}

// ======================= conv1 fused (light): softmax + aggregate only ===========
__global__ __launch_bounds__(256) void k_fused1(
    const int* __restrict__ rowptr, const int2* __restrict__ epk,
    const float* __restrict__ Lg, const u16* __restrict__ xl,
    const float* __restrict__ bias, u16* __restrict__ out, float* __restrict__ Spart)
{
    int node = blockIdx.x;
    int tid = threadIdx.x;          // global column 0..255
    int h = tid >> 6, lane = tid & 63;
    int beg = rowptr[node], end = rowptr[node + 1];
    float acc = 0.f, dtot = 0.f;
    int j = beg;
    for (; j + 3 < end; j += 4) {
        int2 pA = epk[j], pB = epk[j + 1], pC = epk[j + 2], pD = epk[j + 3];
        float g1 = Lg[((size_t)j << 2) + h];
        float g2 = Lg[((size_t)j << 2) + 4 + h];
        float g3 = Lg[((size_t)j << 2) + 8 + h];
        float g4 = Lg[((size_t)j << 2) + 12 + h];
        float xA = b2f(xl[((u32)pA.y << 8) + tid]);
        float xB = b2f(xl[((u32)pB.y << 8) + tid]);
        float xC = b2f(xl[((u32)pC.y << 8) + tid]);
        float xD = b2f(xl[((u32)pD.y << 8) + tid]);
        float p1 = exp2f(g1), p2 = exp2f(g2), p3 = exp2f(g3), p4 = exp2f(g4);
        acc  += (p1 * xA + p2 * xB) + (p3 * xC + p4 * xD);
        dtot += (p1 + p2) + (p3 + p4);
    }
    for (; j < end; j++) {
        int2 p = epk[j];
        float pe = exp2f(Lg[((size_t)j << 2) + h]);
        float xA = b2f(xl[((u32)p.y << 8) + tid]);
        acc += pe * xA; dtot += pe;
    }
    float o = ((end > beg) ? acc / (dtot + EPS_SM) : 0.f) + bias[tid];
    out[((size_t)node << 8) + tid] = f2b(o);
    float s1 = o, s2 = o * o;
    #pragma unroll
    for (int off = 32; off; off >>= 1) { s1 += __shfl_xor(s1, off); s2 += __shfl_xor(s2, off); }
    __shared__ float ls1[4], ls2[4];
    if (lane == 0) { ls1[h] = s1; ls2[h] = s2; }
    __syncthreads();
    if (tid == 0) {
        Spart[(size_t)node * 2]     = ls1[0] + ls1[1] + ls1[2] + ls1[3];
        Spart[(size_t)node * 2 + 1] = ls2[0] + ls2[1] + ls2[2] + ls2[3];
    }
}

// ======================= LayerNorm apply (+ReLU) in-place on bf16 =======================
__global__ void k_ln_apply_relu_b(
    u16* v, const float* __restrict__ w, const float* __restrict__ b,
    const float* __restrict__ S, int M, int C)
{
    int i = blockIdx.x * blockDim.x + threadIdx.x;
    if (i >= M) return;
    float mu = S[0] / (float)M;
    float var = S[1] / (float)M - mu * mu;
    float inv = 1.f / (sqrtf(fmaxf(var, 0.f)) + EPS_LN);
    int c = i % C;
    float y = (b2f(v[i]) - mu) * inv * w[c] + b[c];
    v[i] = f2b(fmaxf(y, 0.f));
}

__global__ void k_ln_out(
    const float* __restrict__ v, const float* __restrict__ w, const float* __restrict__ b,
    const float* __restrict__ S, int M, int C, float* __restrict__ out)
{
    int i = blockIdx.x * blockDim.x + threadIdx.x;
    if (i >= M) return;
    float mu = S[0] / (float)M;
    float var = S[1] / (float)M - mu * mu;
    float inv = 1.f / (sqrtf(fmaxf(var, 0.f)) + EPS_LN);
    int c = i % C;
    out[i] = (v[i] - mu) * inv * w[c] + b[c];
}

// ======================= conv2 node transform via MFMA (bf16 rows padded to 64) =========
__global__ __launch_bounds__(256) void k_node2(
    const u16* __restrict__ h, const u16* __restrict__ Wlt, const u16* __restrict__ Wrt,
    const float* __restrict__ bl, const float* __restrict__ br,
    u16* __restrict__ xlb, u16* __restrict__ xrb)
{
    int w = threadIdx.x >> 6, lane = threadIdx.x & 63;
    int c = lane & 15, kg = lane >> 4;
    int col = (w << 4) + c;                       // 0..63
    s8v bL[8], bR[8];
    #pragma unroll
    for (int ks = 0; ks < 8; ks++) {
        bL[ks] = *(const s8v*)(Wlt + ((u32)col << 8) + (ks << 5) + (kg << 3));
        bR[ks] = *(const s8v*)(Wrt + ((u32)col << 8) + (ks << 5) + (kg << 3));
    }
    float blv = (col < OUTD) ? bl[col] : 0.f;
    float brv = (col < OUTD) ? br[col] : 0.f;
    const int NTILES = N_NODES / 16;   // 3125
    for (int t = blockIdx.x; t < NTILES; t += gridDim.x) {
        int nb = t << 4;
        const u16* hrow = h + ((size_t)(nb + c) << 8) + (kg << 3);
        f4 accL = {blv, blv, blv, blv};
        f4 accR = {brv, brv, brv, brv};
        #pragma unroll
        for (int ks = 0; ks < 8; ks++) {
            s8v a = *(const s8v*)(hrow + (ks << 5));
            accL = __builtin_amdgcn_mfma_f32_16x16x32_bf16(a, bL[ks], accL, 0, 0, 0);
            accR = __builtin_amdgcn_mfma_f32_16x16x32_bf16(a, bR[ks], accR, 0, 0, 0);
        }
        #pragma unroll
        for (int i = 0; i < 4; i++) {
            int node = nb + (kg << 2) + i;
            xlb[((u32)node << 6) + col] = f2b(accL[i]);
            xrb[((u32)node << 6) + col] = f2b(accR[i]);
        }
    }
}

// ======================= conv2 edge logits via MFMA (index-prefetch pipeline) ==========
__global__ __launch_bounds__(256) void k_logits2(
    const int2* __restrict__ epk, const int* __restrict__ dstc,
    const u32* __restrict__ eah, const u16* __restrict__ xlb, const u16* __restrict__ xrb,
    const u32* __restrict__ Weh, const float* __restrict__ atts,
    float* __restrict__ Lg2)
{
    int lane = threadIdx.x & 63;
    int er = lane & 15, grp = lane >> 4;
    hf8 wA[4];
    #pragma unroll
    for (int ct = 0; ct < 4; ct++) {
        uint4 q;
        q.x = Weh[(grp * 4 + 0) * 64 + ct * 16 + er];
        q.y = Weh[(grp * 4 + 1) * 64 + ct * 16 + er];
        q.z = Weh[(grp * 4 + 2) * 64 + ct * 16 + er];
        q.w = Weh[(grp * 4 + 3) * 64 + ct * 16 + er];
        wA[ct] = __builtin_bit_cast(hf8, q);
    }
    int wid = blockIdx.x * 4 + (threadIdx.x >> 6);
    int nw = gridDim.x * 4;
    const int NT = N_EDGES / 16;
    const char* eab = (const char*)eah;
    const f4 zero = {0.f, 0.f, 0.f, 0.f};
    if (wid >= NT) return;
    int2 p = epk[wid * 16 + er];
    int d = dstc[wid * 16 + er];
    for (int t = wid; t < NT; t += nw) {
        int tn = t + nw;
        int2 pn; int dn;
        if (tn < NT) { pn = epk[tn * 16 + er]; dn = dstc[tn * 16 + er]; }
        int j = t * 16 + er;
        hf8 bfrag = *(const hf8*)(eab + (u32)p.x + (grp << 4));
        const u16* xlp = xlb + ((u32)p.y << 6);
        const u16* xrp = xrb + ((u32)d << 6);
        float tot = 0.f;
        #pragma unroll
        for (int ct = 0; ct < 4; ct++) {
            int c0 = ct * 16 + grp * 4;
            f4 z = __builtin_amdgcn_mfma_f32_16x16x32_f16(wA[ct], bfrag, zero, 0, 0, 0);
            uint2 ql = *(const uint2*)(xlp + c0);
            uint2 qr = *(const uint2*)(xrp + c0);
            float4 av = *(const float4*)(atts + c0);
            float z0 = z[0] + __uint_as_float(ql.x << 16)        + __uint_as_float(qr.x << 16);
            float z1 = z[1] + __uint_as_float(ql.x & 0xFFFF0000u) + __uint_as_float(qr.x & 0xFFFF0000u);
            float z2 = z[2] + __uint_as_float(ql.y << 16)        + __uint_as_float(qr.y << 16);
            float z3 = z[3] + __uint_as_float(ql.y & 0xFFFF0000u) + __uint_as_float(qr.y & 0xFFFF0000u);
            tot += av.x * fmaxf(z0, NEG * z0) + av.y * fmaxf(z1, NEG * z1)
                 + av.z * fmaxf(z2, NEG * z2) + av.w * fmaxf(z3, NEG * z3);
        }
        tot += __shfl_xor(tot, 16);
        tot += __shfl_xor(tot, 32);
        if (lane < 16) Lg2[j] = tot;   // 64B coalesced per tile
        p = pn; d = dn;
    }
}

// ======================= conv2 fused (light): softmax + aggregate only ===========
__global__ __launch_bounds__(256) void k_fused2(
    const int* __restrict__ rowptr, const int2* __restrict__ epk,
    const float* __restrict__ Lg2, const u16* __restrict__ xlb,
    const float* __restrict__ bias, float* __restrict__ out, float* __restrict__ Spart)
{
    int w = threadIdx.x >> 6, lane = threadIdx.x & 63;
    int node = blockIdx.x * 4 + w;
    bool col = lane < OUTD;
    int beg = rowptr[node], end = rowptr[node + 1];
    float acc = 0.f, dtot = 0.f;
    int j = beg;
    for (; j + 3 < end; j += 4) {
        int2 p0 = epk[j], p1 = epk[j + 1], p2 = epk[j + 2], p3 = epk[j + 3];
        float g0 = Lg2[j], g1 = Lg2[j + 1], g2 = Lg2[j + 2], g3 = Lg2[j + 3];
        float x0 = b2f(xlb[((u32)p0.y << 6) + lane]);
        float x1 = b2f(xlb[((u32)p1.y << 6) + lane]);
        float x2 = b2f(xlb[((u32)p2.y << 6) + lane]);
        float x3 = b2f(xlb[((u32)p3.y << 6) + lane]);
        float e0 = exp2f(g0), e1 = exp2f(g1), e2 = exp2f(g2), e3 = exp2f(g3);
        acc  += (e0 * x0 + e1 * x1) + (e2 * x2 + e3 * x3);
        dtot += (e0 + e1) + (e2 + e3);
    }
    for (; j < end; j++) {
        int2 p = epk[j];
        float e = exp2f(Lg2[j]);
        float xv = b2f(xlb[((u32)p.y << 6) + lane]);
        acc += e * xv; dtot += e;
    }
    float s1 = 0.f, s2 = 0.f;
    if (col) {
        float o = ((end > beg) ? acc / (dtot + EPS_SM) : 0.f) + bias[lane];
        out[(u32)node * OUTD + lane] = o;
        s1 = o; s2 = o * o;
    }
    #pragma unroll
    for (int off = 32; off; off >>= 1) { s1 += __shfl_xor(s1, off); s2 += __shfl_xor(s2, off); }
    __shared__ float ls1[4], ls2[4];
    if (lane == 0) { ls1[w] = s1; ls2[w] = s2; }
    __syncthreads();
    if (threadIdx.x == 0) {
        Spart[(size_t)blockIdx.x * 2]     = ls1[0] + ls1[1] + ls1[2] + ls1[3];
        Spart[(size_t)blockIdx.x * 2 + 1] = ls2[0] + ls2[1] + ls2[2] + ls2[3];
    }
}

extern "C" void kernel_launch(void* const* d_in, const int* in_sizes, int n_in,
                              void* d_out, int out_size, void* d_ws, size_t ws_size,
                              hipStream_t stream)
{
    const int*   x    = (const int*)d_in[0];
    const int*   ei   = (const int*)d_in[1];
    const int*   srcA = ei;
    const int*   dstA = ei + N_EDGES;
    const float* ea   = (const float*)d_in[2];
    const float* emb  = (const float*)d_in[3];
    const float* Wl1  = (const float*)d_in[4];
    const float* bl1  = (const float*)d_in[5];
    const float* Wr1  = (const float*)d_in[6];
    const float* br1  = (const float*)d_in[7];
    const float* We1  = (const float*)d_in[8];
    const float* att1 = (const float*)d_in[9];
    const float* bias1= (const float*)d_in[10];
    const float* ln1w = (const float*)d_in[11];
    const float* ln1b = (const float*)d_in[12];
    const float* Wl2  = (const float*)d_in[13];
    const float* bl2  = (const float*)d_in[14];
    const float* Wr2  = (const float*)d_in[15];
    const float* br2  = (const float*)d_in[16];
    const float* We2  = (const float*)d_in[17];
    const float* att2 = (const float*)d_in[18];
    const float* bias2= (const float*)d_in[19];
    const float* ln2w = (const float*)d_in[20];
    const float* ln2b = (const float*)d_in[21];

    // workspace layout (float-slot offsets); peak 31,000,000 slots = 124.0 MB
    float* W = (float*)d_ws;
    u16*   xl1b    = (u16*)W;                      // [0, 6.4M)
    u16*   xr1b    = (u16*)(W + 6400000);          // [6.4M, 12.8M)
    u16*   out1b   = (u16*)(W + 12800000);         // [12.8M, 19.2M)  bf16, h1 in place
    u32*   eah     = (u32*)(W + 19200000);         // E*16 u32 [19.2M, 27.2M)
    int2*  epk     = (int2*)(W + 27200000);        // [27.2M, 28.2M)
    int*   rowptr  = (int*)(W + 28200000);         // 50,001 ints, 60k slots
    int*   cnt     = (int*)(W + 28260000);         // N
    int*   cursor  = (int*)(W + 28310000);         // N
    float* Spart   = W + 28360000;                 // 2*N
    float* S       = W + 28460000;                 // 4
    u32*   Weh1    = (u32*)(W + 28470000);         // 16*256 = 4096 (k2>=14 zero)
    u32*   Weh2    = (u32*)(W + 28480000);         // 16*64  = 1024 (padded)
    float* atts1   = W + 28481100;                 // 256
    float* atts2   = W + 28481600;                 // 64
    int*   dstc    = (int*)(W + 28482000);         // E ints = 500k slots [28.482M, 28.982M)
    u16*   Wlt2    = (u16*)(W + 28982000);         // 64*256 u16 = 8192 slots
    u16*   Wrt2    = (u16*)(W + 28991000);         // 64*256 u16 = 8192 slots
    float* Lg      = W + 29000000;                 // E*4 f32 [29M, 31M)  (conv1, written by logits1)
    // pre-conv1 transients (dead before logits1 writes Lg; parked inside Lg region):
    u16*   embb    = (u16*)(W + 29000000);         // N*64 u16 = 1.6M slots [29.0M, 30.6M)
    u16*   Wlt1    = (u16*)(W + 30600000);         // 256*64 u16 = 8192 slots
    u16*   Wrt1    = (u16*)(W + 30610000);         // 256*64 u16 = 8192 slots
    // conv2 reuse (liveness: xl1b/xr1b dead after fused1; Lg dead after fused1):
    u16*   xl2b    = (u16*)W;                      // N*64 u16 [0, 1.6M)
    u16*   xr2b    = (u16*)(W + 1600000);          // N*64 u16 [1.6M, 3.2M)
    float* out2    = W + 3200000;                  // N*50 f32 [3.2M, 5.7M)
    float* Lg2     = W + 29000000;                 // E f32 (reuses Lg region)
    u16*   h1      = out1b;

    // init (zeroing + ea f16 + We f16 pack + emb bf16 pack + att*log2e) + W transpose pack + CSR
    k_init<<<(N_EDGES * 8 + 255) / 256, 256, 0, stream>>>(cnt, cursor, S, ea, eah,
                                                          We1, We2, Weh1, Weh2,
                                                          att1, att2, atts1, atts2,
                                                          emb, embb);
    k_packw<<<128, 256, 0, stream>>>(Wl1, Wr1, Wlt1, Wrt1, Wl2, Wr2, Wlt2, Wrt2);
    k_hist<<<(N_EDGES + 255) / 256, 256, 0, stream>>>(dstA, cnt);
    k_scan<<<1, 1024, 0, stream>>>(cnt, rowptr);
    k_scatter<<<(N_EDGES + 255) / 256, 256, 0, stream>>>(srcA, dstA, rowptr, cursor, epk, dstc);

    // conv1
    k_node1<<<1024, 256, 0, stream>>>(x, embb, Wlt1, Wrt1, bl1, br1, xl1b, xr1b);
    k_logits1<<<1024, 256, 0, stream>>>(epk, dstc, eah, xl1b, xr1b, Weh1, atts1, Lg);
    k_fused1<<<N_NODES, 256, 0, stream>>>(rowptr, epk, Lg, xl1b, bias1, out1b, Spart);
    k_sumpart<<<32, 256, 0, stream>>>(Spart, N_NODES, S);
    k_ln_apply_relu_b<<<(N_NODES * F1 + 255) / 256, 256, 0, stream>>>(h1, ln1w, ln1b, S, N_NODES * F1, F1);

    // conv2
    k_node2<<<1024, 256, 0, stream>>>(h1, Wlt2, Wrt2, bl2, br2, xl2b, xr2b);
    k_logits2<<<1024, 256, 0, stream>>>(epk, dstc, eah, xl2b, xr2b, Weh2, atts2, Lg2);
    k_fused2<<<N_NODES / 4, 256, 0, stream>>>(rowptr, epk, Lg2, xl2b, bias2, out2, Spart);
    k_sumpart<<<32, 256, 0, stream>>>(Spart, N_NODES / 4, S + 2);
    k_ln_out<<<(N_NODES * OUTD + 255) / 256, 256, 0, stream>>>(out2, ln2w, ln2b, S + 2, N_NODES * OUTD, OUTD, (float*)d_out);
}

// Round 12
// 526.154 us; speedup vs baseline: 1.2775x; 1.1219x over previous
//
#include <hip/hip_runtime.h>

#define N_NODES 50000
#define N_EDGES 500000
#define EMB 50
#define HID 64
#define OUTD 50
#define EDIM 28
#define HEADS 4
#define F1 256              // HEADS*HID
#define NEG 0.2f
#define EPS_SM 1e-16f
#define EPS_LN 1e-5f
#define LOG2E 1.4426950408889634f
#define SCAN_B 196          // ceil(N_NODES/256)

typedef unsigned short u16;
typedef unsigned int u32;
typedef _Float16 hf;
typedef hf h2 __attribute__((ext_vector_type(2)));
typedef hf hf8 __attribute__((ext_vector_type(8)));
typedef float f4 __attribute__((ext_vector_type(4)));
typedef short s8v __attribute__((ext_vector_type(8)));   // 8 bf16 (4 VGPRs)

__device__ __forceinline__ float b2f(u16 u) { return __uint_as_float(((u32)u) << 16); }
__device__ __forceinline__ u16 f2b(float f) {
    u32 u = __float_as_uint(f);
    u32 r = (u + 0x7FFFu + ((u >> 16) & 1u)) >> 16;
    return (u16)r;
}
__device__ __forceinline__ h2 uq(u32 u) { return __builtin_bit_cast(h2, u); }
__device__ __forceinline__ u32 hpack(float a, float b) {
    h2 p = {(hf)a, (hf)b};
    return __builtin_bit_cast(u32, p);
}
__device__ __forceinline__ float lrelu(float x) { return x > 0.f ? x : NEG * x; }

// ======= init: zero cnt/cursor/S + ea->f16 rows (zero-padded to 32) + We->f16 packed
//         + emb->bf16 rows padded to 64 + att*log2e =======
__global__ void k_init(int* __restrict__ cnt, int* __restrict__ cursor, float* __restrict__ S,
                       const float* __restrict__ a, u32* __restrict__ o,
                       const float* __restrict__ We1, const float* __restrict__ We2,
                       u32* __restrict__ Weh1, u32* __restrict__ Weh2,
                       const float* __restrict__ att1, const float* __restrict__ att2,
                       float* __restrict__ atts1, float* __restrict__ atts2,
                       const float* __restrict__ emb, u16* __restrict__ embb) {
    int i = blockIdx.x * blockDim.x + threadIdx.x;
    if (i < N_NODES) cnt[i] = 0;
    else if (i < 2 * N_NODES) cursor[i - N_NODES] = 0;
    else if (i < 2 * N_NODES + 4) S[i - 2 * N_NODES] = 0.f;
    if (i < F1 * 16) {               // Weh1[k2*256+c], k2 in [0,16), zero-padded k2>=14
        int k2 = i >> 8, c = i & 255;
        Weh1[i] = (k2 < 14) ? hpack(We1[(2 * k2) * F1 + c], We1[(2 * k2 + 1) * F1 + c]) : 0u;
    } else if (i < F1 * 16 + 64 * 16) {  // Weh2[k2*64+c], k2>=14 or c>=OUTD zero-padded
        int j = i - F1 * 16;
        int k2 = j >> 6, c = j & 63;
        Weh2[j] = (k2 < 14 && c < OUTD) ? hpack(We2[(2 * k2) * OUTD + c], We2[(2 * k2 + 1) * OUTD + c]) : 0u;
    } else {
        int ja = i - (F1 * 16 + 64 * 16);
        if (ja < 256) atts1[ja] = att1[ja] * LOG2E;
        else if (ja < 320) {
            int c = ja - 256;
            atts2[c] = (c < OUTD) ? att2[c] * LOG2E : 0.f;
        }
    }
    if (i < N_NODES * 64) {          // embb[node][64] bf16, k>=EMB zero
        int node = i >> 6, k = i & 63;
        embb[i] = (k < EMB) ? f2b(emb[(size_t)node * EMB + k]) : (u16)0;
    }
    if (i < N_EDGES * 8) {           // 8 parts/row: parts 0..6 pack ea, part 7 zero-pads k=28..31
        int e = i >> 3, part = i & 7;
        if (part < 7) {
            float4 v = *(const float4*)(a + (size_t)e * EDIM + part * 4);
            *(uint2*)(o + (size_t)e * 16 + part * 2) = make_uint2(hpack(v.x, v.y), hpack(v.z, v.w));
        } else {
            *(uint2*)(o + (size_t)e * 16 + 14) = make_uint2(0u, 0u);
        }
    }
}

// ======= pack W transposed bf16 for MFMA node kernels =======
__global__ void k_packw(const float* __restrict__ Wl1, const float* __restrict__ Wr1,
                        u16* __restrict__ Wlt1, u16* __restrict__ Wrt1,
                        const float* __restrict__ Wl2, const float* __restrict__ Wr2,
                        u16* __restrict__ Wlt2, u16* __restrict__ Wrt2) {
    int i = blockIdx.x * blockDim.x + threadIdx.x;
    if (i < 256 * 64) {
        int c = i >> 6, k = i & 63;
        Wlt1[i] = (k < EMB) ? f2b(Wl1[k * F1 + c]) : (u16)0;
        Wrt1[i] = (k < EMB) ? f2b(Wr1[k * F1 + c]) : (u16)0;
    } else if (i < 2 * 256 * 64) {
        int j = i - 256 * 64;
        int c = j >> 8, k = j & 255;
        Wlt2[j] = (c < OUTD) ? f2b(Wl2[k * OUTD + c]) : (u16)0;
        Wrt2[j] = (c < OUTD) ? f2b(Wr2[k * OUTD + c]) : (u16)0;
    }
}

// ======================= CSR build =======================
__global__ void k_hist(const int* __restrict__ dst, int* __restrict__ cnt) {
    int e = blockIdx.x * blockDim.x + threadIdx.x;
    if (e < N_EDGES) atomicAdd(&cnt[dst[e]], 1);
}

// --- 3-phase parallel scan (replaces single-block k_scan) ---
__global__ __launch_bounds__(256) void k_scan1(const int* __restrict__ cnt, int* __restrict__ bsum) {
    int i = blockIdx.x * 256 + threadIdx.x;
    int v = (i < N_NODES) ? cnt[i] : 0;
    #pragma unroll
    for (int off = 32; off; off >>= 1) v += __shfl_xor(v, off);
    __shared__ int ws[4];
    if ((threadIdx.x & 63) == 0) ws[threadIdx.x >> 6] = v;
    __syncthreads();
    if (threadIdx.x == 0) bsum[blockIdx.x] = ws[0] + ws[1] + ws[2] + ws[3];
}

__global__ __launch_bounds__(256) void k_scan2(int* __restrict__ bsum) {
    __shared__ int lds[256];
    int tid = threadIdx.x;
    int v = (tid < SCAN_B) ? bsum[tid] : 0;
    lds[tid] = v;
    __syncthreads();
    for (int off = 1; off < 256; off <<= 1) {
        int t = (tid >= off) ? lds[tid - off] : 0;
        __syncthreads();
        lds[tid] += t;
        __syncthreads();
    }
    if (tid < SCAN_B) bsum[tid] = lds[tid] - v;   // exclusive
}

__global__ __launch_bounds__(256) void k_scan3(const int* __restrict__ cnt, const int* __restrict__ bsum,
                                               int* __restrict__ rowptr) {
    __shared__ int lds[256];
    int tid = threadIdx.x;
    int i = blockIdx.x * 256 + tid;
    int v = (i < N_NODES) ? cnt[i] : 0;
    lds[tid] = v;
    __syncthreads();
    for (int off = 1; off < 256; off <<= 1) {
        int t = (tid >= off) ? lds[tid - off] : 0;
        __syncthreads();
        lds[tid] += t;
        __syncthreads();
    }
    int incl = lds[tid];
    int base = bsum[blockIdx.x];
    if (i < N_NODES) rowptr[i] = base + incl - v;
    if (i == N_NODES - 1) rowptr[N_NODES] = base + incl;
}

// epk.x = e*64 (byte offset into eah rows), epk.y = src index; dstc[j] = dst node
__global__ void k_scatter(const int* __restrict__ src, const int* __restrict__ dst,
                          const int* __restrict__ rowptr, int* __restrict__ cursor,
                          int2* __restrict__ epk, int* __restrict__ dstc) {
    int e = blockIdx.x * blockDim.x + threadIdx.x;
    if (e >= N_EDGES) return;
    int d = dst[e];
    int pos = atomicAdd(&cursor[d], 1);
    int j = rowptr[d] + pos;
    epk[j] = make_int2(e << 6, src[e]);
    dstc[j] = d;
}

// ======================= partial-sum reducer =======================
__global__ __launch_bounds__(256) void k_sumpart(const float* __restrict__ P, int n, float* __restrict__ S) {
    float s1 = 0.f, s2 = 0.f;
    int stride = gridDim.x * blockDim.x;
    for (int i = blockIdx.x * blockDim.x + threadIdx.x; i < n; i += stride) {
        s1 += P[2 * i]; s2 += P[2 * i + 1];
    }
    #pragma unroll
    for (int off = 32; off; off >>= 1) { s1 += __shfl_xor(s1, off); s2 += __shfl_xor(s2, off); }
    __shared__ float w1[4], w2[4];
    int w = threadIdx.x >> 6;
    if ((threadIdx.x & 63) == 0) { w1[w] = s1; w2[w] = s2; }
    __syncthreads();
    if (threadIdx.x == 0) {
        atomicAdd(S,     w1[0] + w1[1] + w1[2] + w1[3]);
        atomicAdd(S + 1, w2[0] + w2[1] + w2[2] + w2[3]);
    }
}

// ======================= conv1 node transform via MFMA =======================
__global__ __launch_bounds__(256) void k_node1(
    const int* __restrict__ x, const u16* __restrict__ embb,
    const u16* __restrict__ Wlt, const u16* __restrict__ Wrt,
    const float* __restrict__ bl, const float* __restrict__ br,
    u16* __restrict__ xl, u16* __restrict__ xr)
{
    int w = threadIdx.x >> 6, lane = threadIdx.x & 63;
    int c = lane & 15, kg = lane >> 4;
    s8v bL[4][2], bR[4][2];
    float blv[4], brv[4];
    #pragma unroll
    for (int ct = 0; ct < 4; ct++) {
        int col = (w << 6) + (ct << 4) + c;
        #pragma unroll
        for (int ks = 0; ks < 2; ks++) {
            bL[ct][ks] = *(const s8v*)(Wlt + ((u32)col << 6) + (ks << 5) + (kg << 3));
            bR[ct][ks] = *(const s8v*)(Wrt + ((u32)col << 6) + (ks << 5) + (kg << 3));
        }
        blv[ct] = bl[col];
        brv[ct] = br[col];
    }
    const int NTILES = N_NODES / 16;   // 3125
    for (int t = blockIdx.x; t < NTILES; t += gridDim.x) {
        int nb = t << 4;
        int xi = x[nb + c];
        const u16* er = embb + ((u32)xi << 6);
        s8v a0 = *(const s8v*)(er + (kg << 3));
        s8v a1 = *(const s8v*)(er + 32 + (kg << 3));
        #pragma unroll
        for (int ct = 0; ct < 4; ct++) {
            int col = (w << 6) + (ct << 4) + c;
            f4 accL = {blv[ct], blv[ct], blv[ct], blv[ct]};
            f4 accR = {brv[ct], brv[ct], brv[ct], brv[ct]};
            accL = __builtin_amdgcn_mfma_f32_16x16x32_bf16(a0, bL[ct][0], accL, 0, 0, 0);
            accL = __builtin_amdgcn_mfma_f32_16x16x32_bf16(a1, bL[ct][1], accL, 0, 0, 0);
            accR = __builtin_amdgcn_mfma_f32_16x16x32_bf16(a0, bR[ct][0], accR, 0, 0, 0);
            accR = __builtin_amdgcn_mfma_f32_16x16x32_bf16(a1, bR[ct][1], accR, 0, 0, 0);
            #pragma unroll
            for (int i = 0; i < 4; i++) {
                int node = nb + (kg << 2) + i;
                xl[((size_t)node << 8) + col] = f2b(accL[i]);
                xr[((size_t)node << 8) + col] = f2b(accR[i]);
            }
        }
    }
}

// ======================= conv1 edge logits via MFMA (index+bfrag prefetch) ============
__global__ __launch_bounds__(256) void k_logits1(
    const int2* __restrict__ epk, const int* __restrict__ dstc,
    const u32* __restrict__ eah, const u16* __restrict__ xl, const u16* __restrict__ xr,
    const u32* __restrict__ Weh, const float* __restrict__ atts,
    float* __restrict__ Lg)
{
    int lane = threadIdx.x & 63;
    int er = lane & 15, grp = lane >> 4;
    hf8 wA[16];
    #pragma unroll
    for (int ct = 0; ct < 16; ct++) {
        uint4 q;
        q.x = Weh[(grp * 4 + 0) * 256 + ct * 16 + er];
        q.y = Weh[(grp * 4 + 1) * 256 + ct * 16 + er];
        q.z = Weh[(grp * 4 + 2) * 256 + ct * 16 + er];
        q.w = Weh[(grp * 4 + 3) * 256 + ct * 16 + er];
        wA[ct] = __builtin_bit_cast(hf8, q);
    }
    int wid = blockIdx.x * 4 + (threadIdx.x >> 6);
    int nw = gridDim.x * 4;
    const int NT = N_EDGES / 16;
    const char* eab = (const char*)eah;
    const f4 zero = {0.f, 0.f, 0.f, 0.f};
    if (wid >= NT) return;
    int2 p = epk[wid * 16 + er];
    int d = dstc[wid * 16 + er];
    hf8 bfrag = *(const hf8*)(eab + (u32)p.x + (grp << 4));
    for (int t = wid; t < NT; t += nw) {
        int tn = t + nw;
        int2 pn; int dn; hf8 bfn;
        if (tn < NT) {
            pn = epk[tn * 16 + er];
            dn = dstc[tn * 16 + er];
            bfn = *(const hf8*)(eab + (u32)pn.x + (grp << 4));
        }
        int j = t * 16 + er;
        const u16* xlp = xl + ((u32)p.y << 8);
        const u16* xrp = xr + ((u32)d << 8);
        float part0 = 0.f, part1 = 0.f, part2 = 0.f, part3 = 0.f;
        #pragma unroll
        for (int ct = 0; ct < 16; ct++) {
            int c0 = ct * 16 + grp * 4;
            f4 z = __builtin_amdgcn_mfma_f32_16x16x32_f16(wA[ct], bfrag, zero, 0, 0, 0);
            uint2 ql = *(const uint2*)(xlp + c0);
            uint2 qr = *(const uint2*)(xrp + c0);
            float4 av = *(const float4*)(atts + c0);
            float z0 = z[0] + __uint_as_float(ql.x << 16)        + __uint_as_float(qr.x << 16);
            float z1 = z[1] + __uint_as_float(ql.x & 0xFFFF0000u) + __uint_as_float(qr.x & 0xFFFF0000u);
            float z2 = z[2] + __uint_as_float(ql.y << 16)        + __uint_as_float(qr.y << 16);
            float z3 = z[3] + __uint_as_float(ql.y & 0xFFFF0000u) + __uint_as_float(qr.y & 0xFFFF0000u);
            float s = av.x * fmaxf(z0, NEG * z0) + av.y * fmaxf(z1, NEG * z1)
                    + av.z * fmaxf(z2, NEG * z2) + av.w * fmaxf(z3, NEG * z3);
            if      (ct < 4)  part0 += s;
            else if (ct < 8)  part1 += s;
            else if (ct < 12) part2 += s;
            else              part3 += s;
        }
        part0 += __shfl_xor(part0, 16); part0 += __shfl_xor(part0, 32);
        part1 += __shfl_xor(part1, 16); part1 += __shfl_xor(part1, 32);
        part2 += __shfl_xor(part2, 16); part2 += __shfl_xor(part2, 32);
        part3 += __shfl_xor(part3, 16); part3 += __shfl_xor(part3, 32);
        float v01 = (grp & 1) ? part1 : part0;
        float v23 = (grp & 1) ? part3 : part2;
        float v = (grp & 2) ? v23 : v01;
        Lg[((size_t)j << 2) + grp] = v;   // [j][h] layout, coalesced 256B/wave
        p = pn; d = dn; bfrag = bfn;
    }
}

// ======================= conv1 fused (light): softmax + aggregate only ===========
__global__ __launch_bounds__(256) void k_fused1(
    const int* __restrict__ rowptr, const int2* __restrict__ epk,
    const float* __restrict__ Lg, const u16* __restrict__ xl,
    const float* __restrict__ bias, u16* __restrict__ out, float* __restrict__ Spart)
{
    int node = blockIdx.x;
    int tid = threadIdx.x;          // global column 0..255
    int h = tid >> 6, lane = tid & 63;
    int beg = rowptr[node], end = rowptr[node + 1];
    float acc = 0.f, dtot = 0.f;
    int j = beg;
    for (; j + 3 < end; j += 4) {
        int2 pA = epk[j], pB = epk[j + 1], pC = epk[j + 2], pD = epk[j + 3];
        float g1 = Lg[((size_t)j << 2) + h];
        float g2 = Lg[((size_t)j << 2) + 4 + h];
        float g3 = Lg[((size_t)j << 2) + 8 + h];
        float g4 = Lg[((size_t)j << 2) + 12 + h];
        float xA = b2f(xl[((u32)pA.y << 8) + tid]);
        float xB = b2f(xl[((u32)pB.y << 8) + tid]);
        float xC = b2f(xl[((u32)pC.y << 8) + tid]);
        float xD = b2f(xl[((u32)pD.y << 8) + tid]);
        float p1 = exp2f(g1), p2 = exp2f(g2), p3 = exp2f(g3), p4 = exp2f(g4);
        acc  += (p1 * xA + p2 * xB) + (p3 * xC + p4 * xD);
        dtot += (p1 + p2) + (p3 + p4);
    }
    for (; j < end; j++) {
        int2 p = epk[j];
        float pe = exp2f(Lg[((size_t)j << 2) + h]);
        float xA = b2f(xl[((u32)p.y << 8) + tid]);
        acc += pe * xA; dtot += pe;
    }
    float o = ((end > beg) ? acc / (dtot + EPS_SM) : 0.f) + bias[tid];
    out[((size_t)node << 8) + tid] = f2b(o);
    float s1 = o, s2 = o * o;
    #pragma unroll
    for (int off = 32; off; off >>= 1) { s1 += __shfl_xor(s1, off); s2 += __shfl_xor(s2, off); }
    __shared__ float ls1[4], ls2[4];
    if (lane == 0) { ls1[h] = s1; ls2[h] = s2; }
    __syncthreads();
    if (tid == 0) {
        Spart[(size_t)node * 2]     = ls1[0] + ls1[1] + ls1[2] + ls1[3];
        Spart[(size_t)node * 2 + 1] = ls2[0] + ls2[1] + ls2[2] + ls2[3];
    }
}

// ======================= LayerNorm apply (+ReLU) in-place on bf16 =======================
__global__ void k_ln_apply_relu_b(
    u16* v, const float* __restrict__ w, const float* __restrict__ b,
    const float* __restrict__ S, int M, int C)
{
    int i = blockIdx.x * blockDim.x + threadIdx.x;
    if (i >= M) return;
    float mu = S[0] / (float)M;
    float var = S[1] / (float)M - mu * mu;
    float inv = 1.f / (sqrtf(fmaxf(var, 0.f)) + EPS_LN);
    int c = i % C;
    float y = (b2f(v[i]) - mu) * inv * w[c] + b[c];
    v[i] = f2b(fmaxf(y, 0.f));
}

__global__ void k_ln_out(
    const float* __restrict__ v, const float* __restrict__ w, const float* __restrict__ b,
    const float* __restrict__ S, int M, int C, float* __restrict__ out)
{
    int i = blockIdx.x * blockDim.x + threadIdx.x;
    if (i >= M) return;
    float mu = S[0] / (float)M;
    float var = S[1] / (float)M - mu * mu;
    float inv = 1.f / (sqrtf(fmaxf(var, 0.f)) + EPS_LN);
    int c = i % C;
    out[i] = (v[i] - mu) * inv * w[c] + b[c];
}

// ======================= conv2 node transform via MFMA (bf16 rows padded to 64) =========
__global__ __launch_bounds__(256) void k_node2(
    const u16* __restrict__ h, const u16* __restrict__ Wlt, const u16* __restrict__ Wrt,
    const float* __restrict__ bl, const float* __restrict__ br,
    u16* __restrict__ xlb, u16* __restrict__ xrb)
{
    int w = threadIdx.x >> 6, lane = threadIdx.x & 63;
    int c = lane & 15, kg = lane >> 4;
    int col = (w << 4) + c;                       // 0..63
    s8v bL[8], bR[8];
    #pragma unroll
    for (int ks = 0; ks < 8; ks++) {
        bL[ks] = *(const s8v*)(Wlt + ((u32)col << 8) + (ks << 5) + (kg << 3));
        bR[ks] = *(const s8v*)(Wrt + ((u32)col << 8) + (ks << 5) + (kg << 3));
    }
    float blv = (col < OUTD) ? bl[col] : 0.f;
    float brv = (col < OUTD) ? br[col] : 0.f;
    const int NTILES = N_NODES / 16;   // 3125
    for (int t = blockIdx.x; t < NTILES; t += gridDim.x) {
        int nb = t << 4;
        const u16* hrow = h + ((size_t)(nb + c) << 8) + (kg << 3);
        f4 accL = {blv, blv, blv, blv};
        f4 accR = {brv, brv, brv, brv};
        #pragma unroll
        for (int ks = 0; ks < 8; ks++) {
            s8v a = *(const s8v*)(hrow + (ks << 5));
            accL = __builtin_amdgcn_mfma_f32_16x16x32_bf16(a, bL[ks], accL, 0, 0, 0);
            accR = __builtin_amdgcn_mfma_f32_16x16x32_bf16(a, bR[ks], accR, 0, 0, 0);
        }
        #pragma unroll
        for (int i = 0; i < 4; i++) {
            int node = nb + (kg << 2) + i;
            xlb[((u32)node << 6) + col] = f2b(accL[i]);
            xrb[((u32)node << 6) + col] = f2b(accR[i]);
        }
    }
}

// ======================= conv2 edge logits via MFMA (index+bfrag prefetch) ==========
__global__ __launch_bounds__(256) void k_logits2(
    const int2* __restrict__ epk, const int* __restrict__ dstc,
    const u32* __restrict__ eah, const u16* __restrict__ xlb, const u16* __restrict__ xrb,
    const u32* __restrict__ Weh, const float* __restrict__ atts,
    float* __restrict__ Lg2)
{
    int lane = threadIdx.x & 63;
    int er = lane & 15, grp = lane >> 4;
    hf8 wA[4];
    #pragma unroll
    for (int ct = 0; ct < 4; ct++) {
        uint4 q;
        q.x = Weh[(grp * 4 + 0) * 64 + ct * 16 + er];
        q.y = Weh[(grp * 4 + 1) * 64 + ct * 16 + er];
        q.z = Weh[(grp * 4 + 2) * 64 + ct * 16 + er];
        q.w = Weh[(grp * 4 + 3) * 64 + ct * 16 + er];
        wA[ct] = __builtin_bit_cast(hf8, q);
    }
    int wid = blockIdx.x * 4 + (threadIdx.x >> 6);
    int nw = gridDim.x * 4;
    const int NT = N_EDGES / 16;
    const char* eab = (const char*)eah;
    const f4 zero = {0.f, 0.f, 0.f, 0.f};
    if (wid >= NT) return;
    int2 p = epk[wid * 16 + er];
    int d = dstc[wid * 16 + er];
    hf8 bfrag = *(const hf8*)(eab + (u32)p.x + (grp << 4));
    for (int t = wid; t < NT; t += nw) {
        int tn = t + nw;
        int2 pn; int dn; hf8 bfn;
        if (tn < NT) {
            pn = epk[tn * 16 + er];
            dn = dstc[tn * 16 + er];
            bfn = *(const hf8*)(eab + (u32)pn.x + (grp << 4));
        }
        int j = t * 16 + er;
        const u16* xlp = xlb + ((u32)p.y << 6);
        const u16* xrp = xrb + ((u32)d << 6);
        float tot = 0.f;
        #pragma unroll
        for (int ct = 0; ct < 4; ct++) {
            int c0 = ct * 16 + grp * 4;
            f4 z = __builtin_amdgcn_mfma_f32_16x16x32_f16(wA[ct], bfrag, zero, 0, 0, 0);
            uint2 ql = *(const uint2*)(xlp + c0);
            uint2 qr = *(const uint2*)(xrp + c0);
            float4 av = *(const float4*)(atts + c0);
            float z0 = z[0] + __uint_as_float(ql.x << 16)        + __uint_as_float(qr.x << 16);
            float z1 = z[1] + __uint_as_float(ql.x & 0xFFFF0000u) + __uint_as_float(qr.x & 0xFFFF0000u);
            float z2 = z[2] + __uint_as_float(ql.y << 16)        + __uint_as_float(qr.y << 16);
            float z3 = z[3] + __uint_as_float(ql.y & 0xFFFF0000u) + __uint_as_float(qr.y & 0xFFFF0000u);
            tot += av.x * fmaxf(z0, NEG * z0) + av.y * fmaxf(z1, NEG * z1)
                 + av.z * fmaxf(z2, NEG * z2) + av.w * fmaxf(z3, NEG * z3);
        }
        tot += __shfl_xor(tot, 16);
        tot += __shfl_xor(tot, 32);
        if (lane < 16) Lg2[j] = tot;   // 64B coalesced per tile
        p = pn; d = dn; bfrag = bfn;
    }
}

// ======================= conv2 fused (light): softmax + aggregate only ===========
__global__ __launch_bounds__(256) void k_fused2(
    const int* __restrict__ rowptr, const int2* __restrict__ epk,
    const float* __restrict__ Lg2, const u16* __restrict__ xlb,
    const float* __restrict__ bias, float* __restrict__ out, float* __restrict__ Spart)
{
    int w = threadIdx.x >> 6, lane = threadIdx.x & 63;
    int node = blockIdx.x * 4 + w;
    bool col = lane < OUTD;
    int beg = rowptr[node], end = rowptr[node + 1];
    float acc = 0.f, dtot = 0.f;
    int j = beg;
    for (; j + 3 < end; j += 4) {
        int2 p0 = epk[j], p1 = epk[j + 1], p2 = epk[j + 2], p3 = epk[j + 3];
        float g0 = Lg2[j], g1 = Lg2[j + 1], g2 = Lg2[j + 2], g3 = Lg2[j + 3];
        float x0 = b2f(xlb[((u32)p0.y << 6) + lane]);
        float x1 = b2f(xlb[((u32)p1.y << 6) + lane]);
        float x2 = b2f(xlb[((u32)p2.y << 6) + lane]);
        float x3 = b2f(xlb[((u32)p3.y << 6) + lane]);
        float e0 = exp2f(g0), e1 = exp2f(g1), e2 = exp2f(g2), e3 = exp2f(g3);
        acc  += (e0 * x0 + e1 * x1) + (e2 * x2 + e3 * x3);
        dtot += (e0 + e1) + (e2 + e3);
    }
    for (; j < end; j++) {
        int2 p = epk[j];
        float e = exp2f(Lg2[j]);
        float xv = b2f(xlb[((u32)p.y << 6) + lane]);
        acc += e * xv; dtot += e;
    }
    float s1 = 0.f, s2 = 0.f;
    if (col) {
        float o = ((end > beg) ? acc / (dtot + EPS_SM) : 0.f) + bias[lane];
        out[(u32)node * OUTD + lane] = o;
        s1 = o; s2 = o * o;
    }
    #pragma unroll
    for (int off = 32; off; off >>= 1) { s1 += __shfl_xor(s1, off); s2 += __shfl_xor(s2, off); }
    __shared__ float ls1[4], ls2[4];
    if (lane == 0) { ls1[w] = s1; ls2[w] = s2; }
    __syncthreads();
    if (threadIdx.x == 0) {
        Spart[(size_t)blockIdx.x * 2]     = ls1[0] + ls1[1] + ls1[2] + ls1[3];
        Spart[(size_t)blockIdx.x * 2 + 1] = ls2[0] + ls2[1] + ls2[2] + ls2[3];
    }
}

extern "C" void kernel_launch(void* const* d_in, const int* in_sizes, int n_in,
                              void* d_out, int out_size, void* d_ws, size_t ws_size,
                              hipStream_t stream)
{
    const int*   x    = (const int*)d_in[0];
    const int*   ei   = (const int*)d_in[1];
    const int*   srcA = ei;
    const int*   dstA = ei + N_EDGES;
    const float* ea   = (const float*)d_in[2];
    const float* emb  = (const float*)d_in[3];
    const float* Wl1  = (const float*)d_in[4];
    const float* bl1  = (const float*)d_in[5];
    const float* Wr1  = (const float*)d_in[6];
    const float* br1  = (const float*)d_in[7];
    const float* We1  = (const float*)d_in[8];
    const float* att1 = (const float*)d_in[9];
    const float* bias1= (const float*)d_in[10];
    const float* ln1w = (const float*)d_in[11];
    const float* ln1b = (const float*)d_in[12];
    const float* Wl2  = (const float*)d_in[13];
    const float* bl2  = (const float*)d_in[14];
    const float* Wr2  = (const float*)d_in[15];
    const float* br2  = (const float*)d_in[16];
    const float* We2  = (const float*)d_in[17];
    const float* att2 = (const float*)d_in[18];
    const float* bias2= (const float*)d_in[19];
    const float* ln2w = (const float*)d_in[20];
    const float* ln2b = (const float*)d_in[21];

    // workspace layout (float-slot offsets); peak 31,000,000 slots = 124.0 MB
    float* W = (float*)d_ws;
    u16*   xl1b    = (u16*)W;                      // [0, 6.4M)
    u16*   xr1b    = (u16*)(W + 6400000);          // [6.4M, 12.8M)
    u16*   out1b   = (u16*)(W + 12800000);         // [12.8M, 19.2M)  bf16, h1 in place
    u32*   eah     = (u32*)(W + 19200000);         // E*16 u32 [19.2M, 27.2M)
    int2*  epk     = (int2*)(W + 27200000);        // [27.2M, 28.2M)
    int*   rowptr  = (int*)(W + 28200000);         // 50,001 ints, 60k slots
    int*   cnt     = (int*)(W + 28260000);         // N
    int*   cursor  = (int*)(W + 28310000);         // N
    float* Spart   = W + 28360000;                 // 2*N [28.36M, 28.46M)
    float* S       = W + 28460000;                 // 4
    int*   bsum    = (int*)(W + 28461000);         // SCAN_B=196 ints [28.461M, 28.4612M) — gap before Weh1
    u32*   Weh1    = (u32*)(W + 28470000);         // 16*256 = 4096 (k2>=14 zero)
    u32*   Weh2    = (u32*)(W + 28480000);         // 16*64  = 1024 (padded)
    float* atts1   = W + 28481100;                 // 256
    float* atts2   = W + 28481600;                 // 64
    int*   dstc    = (int*)(W + 28482000);         // E ints = 500k slots [28.482M, 28.982M)
    u16*   Wlt2    = (u16*)(W + 28982000);         // 64*256 u16 = 8192 slots [28.982M, 28.9902M)
    u16*   Wrt2    = (u16*)(W + 28991000);         // 64*256 u16 = 8192 slots [28.991M, 28.9992M)
    float* Lg      = W + 29000000;                 // E*4 f32 [29M, 31M)  (conv1, written by logits1)
    // pre-conv1 transients (dead before logits1 writes Lg; parked inside Lg region):
    u16*   embb    = (u16*)(W + 29000000);         // N*64 u16 = 1.6M slots [29.0M, 30.6M)
    u16*   Wlt1    = (u16*)(W + 30600000);         // 256*64 u16 = 8192 slots
    u16*   Wrt1    = (u16*)(W + 30610000);         // 256*64 u16 = 8192 slots
    // conv2 reuse (liveness: xl1b/xr1b dead after fused1; Lg dead after fused1):
    u16*   xl2b    = (u16*)W;                      // N*64 u16 [0, 1.6M)
    u16*   xr2b    = (u16*)(W + 1600000);          // N*64 u16 [1.6M, 3.2M)
    float* out2    = W + 3200000;                  // N*50 f32 [3.2M, 5.7M)
    float* Lg2     = W + 29000000;                 // E f32 (reuses Lg region)
    u16*   h1      = out1b;

    // init (zeroing + ea f16 + We f16 pack + emb bf16 pack + att*log2e) + W transpose pack + CSR
    k_init<<<(N_EDGES * 8 + 255) / 256, 256, 0, stream>>>(cnt, cursor, S, ea, eah,
                                                          We1, We2, Weh1, Weh2,
                                                          att1, att2, atts1, atts2,
                                                          emb, embb);
    k_packw<<<128, 256, 0, stream>>>(Wl1, Wr1, Wlt1, Wrt1, Wl2, Wr2, Wlt2, Wrt2);
    k_hist<<<(N_EDGES + 255) / 256, 256, 0, stream>>>(dstA, cnt);
    k_scan1<<<SCAN_B, 256, 0, stream>>>(cnt, bsum);
    k_scan2<<<1, 256, 0, stream>>>(bsum);
    k_scan3<<<SCAN_B, 256, 0, stream>>>(cnt, bsum, rowptr);
    k_scatter<<<(N_EDGES + 255) / 256, 256, 0, stream>>>(srcA, dstA, rowptr, cursor, epk, dstc);

    // conv1
    k_node1<<<1024, 256, 0, stream>>>(x, embb, Wlt1, Wrt1, bl1, br1, xl1b, xr1b);
    k_logits1<<<1024, 256, 0, stream>>>(epk, dstc, eah, xl1b, xr1b, Weh1, atts1, Lg);
    k_fused1<<<N_NODES, 256, 0, stream>>>(rowptr, epk, Lg, xl1b, bias1, out1b, Spart);
    k_sumpart<<<32, 256, 0, stream>>>(Spart, N_NODES, S);
    k_ln_apply_relu_b<<<(N_NODES * F1 + 255) / 256, 256, 0, stream>>>(h1, ln1w, ln1b, S, N_NODES * F1, F1);

    // conv2
    k_node2<<<1024, 256, 0, stream>>>(h1, Wlt2, Wrt2, bl2, br2, xl2b, xr2b);
    k_logits2<<<1024, 256, 0, stream>>>(epk, dstc, eah, xl2b, xr2b, Weh2, atts2, Lg2);
    k_fused2<<<N_NODES / 4, 256, 0, stream>>>(rowptr, epk, Lg2, xl2b, bias2, out2, Spart);
    k_sumpart<<<32, 256, 0, stream>>>(Spart, N_NODES / 4, S + 2);
    k_ln_out<<<(N_NODES * OUTD + 255) / 256, 256, 0, stream>>>(out2, ln2w, ln2b, S + 2, N_NODES * OUTD, OUTD, (float*)d_out);
}

// Round 13
// 488.559 us; speedup vs baseline: 1.3758x; 1.0769x over previous
//
#include <hip/hip_runtime.h>

#define N_NODES 50000
#define N_EDGES 500000
#define EMB 50
#define HID 64
#define OUTD 50
#define EDIM 28
#define HEADS 4
#define F1 256              // HEADS*HID
#define NEG 0.2f
#define EPS_SM 1e-16f
#define EPS_LN 1e-5f
#define LOG2E 1.4426950408889634f
#define SCAN_B 196          // ceil(N_NODES/256)

typedef unsigned short u16;
typedef unsigned int u32;
typedef _Float16 hf;
typedef hf h2 __attribute__((ext_vector_type(2)));
typedef hf hf8 __attribute__((ext_vector_type(8)));
typedef float f4 __attribute__((ext_vector_type(4)));
typedef short s8v __attribute__((ext_vector_type(8)));   // 8 bf16 (4 VGPRs)

__device__ __forceinline__ float b2f(u16 u) { return __uint_as_float(((u32)u) << 16); }
__device__ __forceinline__ u16 f2b(float f) {
    u32 u = __float_as_uint(f);
    u32 r = (u + 0x7FFFu + ((u >> 16) & 1u)) >> 16;
    return (u16)r;
}
__device__ __forceinline__ h2 uq(u32 u) { return __builtin_bit_cast(h2, u); }
__device__ __forceinline__ u32 hpack(float a, float b) {
    h2 p = {(hf)a, (hf)b};
    return __builtin_bit_cast(u32, p);
}
__device__ __forceinline__ float lrelu(float x) { return x > 0.f ? x : NEG * x; }

// ======= init: zero cnt/cursor/S + ea->f16 rows (zero-padded to 32) + We->f16 packed
//         + emb->bf16 rows padded to 64 + att*log2e =======
__global__ void k_init(int* __restrict__ cnt, int* __restrict__ cursor, float* __restrict__ S,
                       const float* __restrict__ a, u32* __restrict__ o,
                       const float* __restrict__ We1, const float* __restrict__ We2,
                       u32* __restrict__ Weh1, u32* __restrict__ Weh2,
                       const float* __restrict__ att1, const float* __restrict__ att2,
                       float* __restrict__ atts1, float* __restrict__ atts2,
                       const float* __restrict__ emb, u16* __restrict__ embb) {
    int i = blockIdx.x * blockDim.x + threadIdx.x;
    if (i < N_NODES) cnt[i] = 0;
    else if (i < 2 * N_NODES) cursor[i - N_NODES] = 0;
    else if (i < 2 * N_NODES + 4) S[i - 2 * N_NODES] = 0.f;
    if (i < F1 * 16) {               // Weh1[k2*256+c], k2 in [0,16), zero-padded k2>=14
        int k2 = i >> 8, c = i & 255;
        Weh1[i] = (k2 < 14) ? hpack(We1[(2 * k2) * F1 + c], We1[(2 * k2 + 1) * F1 + c]) : 0u;
    } else if (i < F1 * 16 + 64 * 16) {  // Weh2[k2*64+c], k2>=14 or c>=OUTD zero-padded
        int j = i - F1 * 16;
        int k2 = j >> 6, c = j & 63;
        Weh2[j] = (k2 < 14 && c < OUTD) ? hpack(We2[(2 * k2) * OUTD + c], We2[(2 * k2 + 1) * OUTD + c]) : 0u;
    } else {
        int ja = i - (F1 * 16 + 64 * 16);
        if (ja < 256) atts1[ja] = att1[ja] * LOG2E;
        else if (ja < 320) {
            int c = ja - 256;
            atts2[c] = (c < OUTD) ? att2[c] * LOG2E : 0.f;
        }
    }
    if (i < N_NODES * 64) {          // embb[node][64] bf16, k>=EMB zero
        int node = i >> 6, k = i & 63;
        embb[i] = (k < EMB) ? f2b(emb[(size_t)node * EMB + k]) : (u16)0;
    }
    if (i < N_EDGES * 8) {           // 8 parts/row: parts 0..6 pack ea, part 7 zero-pads k=28..31
        int e = i >> 3, part = i & 7;
        if (part < 7) {
            float4 v = *(const float4*)(a + (size_t)e * EDIM + part * 4);
            *(uint2*)(o + (size_t)e * 16 + part * 2) = make_uint2(hpack(v.x, v.y), hpack(v.z, v.w));
        } else {
            *(uint2*)(o + (size_t)e * 16 + 14) = make_uint2(0u, 0u);
        }
    }
}

// ======= pack W transposed bf16 for MFMA node kernels =======
__global__ void k_packw(const float* __restrict__ Wl1, const float* __restrict__ Wr1,
                        u16* __restrict__ Wlt1, u16* __restrict__ Wrt1,
                        const float* __restrict__ Wl2, const float* __restrict__ Wr2,
                        u16* __restrict__ Wlt2, u16* __restrict__ Wrt2) {
    int i = blockIdx.x * blockDim.x + threadIdx.x;
    if (i < 256 * 64) {
        int c = i >> 6, k = i & 63;
        Wlt1[i] = (k < EMB) ? f2b(Wl1[k * F1 + c]) : (u16)0;
        Wrt1[i] = (k < EMB) ? f2b(Wr1[k * F1 + c]) : (u16)0;
    } else if (i < 2 * 256 * 64) {
        int j = i - 256 * 64;
        int c = j >> 8, k = j & 255;
        Wlt2[j] = (c < OUTD) ? f2b(Wl2[k * OUTD + c]) : (u16)0;
        Wrt2[j] = (c < OUTD) ? f2b(Wr2[k * OUTD + c]) : (u16)0;
    }
}

// ======================= CSR build =======================
__global__ void k_hist(const int* __restrict__ dst, int* __restrict__ cnt) {
    int e = blockIdx.x * blockDim.x + threadIdx.x;
    if (e < N_EDGES) atomicAdd(&cnt[dst[e]], 1);
}

// --- 3-phase parallel scan ---
__global__ __launch_bounds__(256) void k_scan1(const int* __restrict__ cnt, int* __restrict__ bsum) {
    int i = blockIdx.x * 256 + threadIdx.x;
    int v = (i < N_NODES) ? cnt[i] : 0;
    #pragma unroll
    for (int off = 32; off; off >>= 1) v += __shfl_xor(v, off);
    __shared__ int ws[4];
    if ((threadIdx.x & 63) == 0) ws[threadIdx.x >> 6] = v;
    __syncthreads();
    if (threadIdx.x == 0) bsum[blockIdx.x] = ws[0] + ws[1] + ws[2] + ws[3];
}

__global__ __launch_bounds__(256) void k_scan2(int* __restrict__ bsum) {
    __shared__ int lds[256];
    int tid = threadIdx.x;
    int v = (tid < SCAN_B) ? bsum[tid] : 0;
    lds[tid] = v;
    __syncthreads();
    for (int off = 1; off < 256; off <<= 1) {
        int t = (tid >= off) ? lds[tid - off] : 0;
        __syncthreads();
        lds[tid] += t;
        __syncthreads();
    }
    if (tid < SCAN_B) bsum[tid] = lds[tid] - v;   // exclusive
}

__global__ __launch_bounds__(256) void k_scan3(const int* __restrict__ cnt, const int* __restrict__ bsum,
                                               int* __restrict__ rowptr) {
    __shared__ int lds[256];
    int tid = threadIdx.x;
    int i = blockIdx.x * 256 + tid;
    int v = (i < N_NODES) ? cnt[i] : 0;
    lds[tid] = v;
    __syncthreads();
    for (int off = 1; off < 256; off <<= 1) {
        int t = (tid >= off) ? lds[tid - off] : 0;
        __syncthreads();
        lds[tid] += t;
        __syncthreads();
    }
    int incl = lds[tid];
    int base = bsum[blockIdx.x];
    if (i < N_NODES) rowptr[i] = base + incl - v;
    if (i == N_NODES - 1) rowptr[N_NODES] = base + incl;
}

// epk.x = e*64 (byte offset into eah rows), epk.y = src index; dstc[j] = dst node
__global__ void k_scatter(const int* __restrict__ src, const int* __restrict__ dst,
                          const int* __restrict__ rowptr, int* __restrict__ cursor,
                          int2* __restrict__ epk, int* __restrict__ dstc) {
    int e = blockIdx.x * blockDim.x + threadIdx.x;
    if (e >= N_EDGES) return;
    int d = dst[e];
    int pos = atomicAdd(&cursor[d], 1);
    int j = rowptr[d] + pos;
    epk[j] = make_int2(e << 6, src[e]);
    dstc[j] = d;
}

// ======================= partial-sum reducer =======================
__global__ __launch_bounds__(256) void k_sumpart(const float* __restrict__ P, int n, float* __restrict__ S) {
    float s1 = 0.f, s2 = 0.f;
    int stride = gridDim.x * blockDim.x;
    for (int i = blockIdx.x * blockDim.x + threadIdx.x; i < n; i += stride) {
        s1 += P[2 * i]; s2 += P[2 * i + 1];
    }
    #pragma unroll
    for (int off = 32; off; off >>= 1) { s1 += __shfl_xor(s1, off); s2 += __shfl_xor(s2, off); }
    __shared__ float w1[4], w2[4];
    int w = threadIdx.x >> 6;
    if ((threadIdx.x & 63) == 0) { w1[w] = s1; w2[w] = s2; }
    __syncthreads();
    if (threadIdx.x == 0) {
        atomicAdd(S,     w1[0] + w1[1] + w1[2] + w1[3]);
        atomicAdd(S + 1, w2[0] + w2[1] + w2[2] + w2[3]);
    }
}

// ======================= conv1 node transform via MFMA =======================
__global__ __launch_bounds__(256) void k_node1(
    const int* __restrict__ x, const u16* __restrict__ embb,
    const u16* __restrict__ Wlt, const u16* __restrict__ Wrt,
    const float* __restrict__ bl, const float* __restrict__ br,
    u16* __restrict__ xl, u16* __restrict__ xr)
{
    int w = threadIdx.x >> 6, lane = threadIdx.x & 63;
    int c = lane & 15, kg = lane >> 4;
    s8v bL[4][2], bR[4][2];
    float blv[4], brv[4];
    #pragma unroll
    for (int ct = 0; ct < 4; ct++) {
        int col = (w << 6) + (ct << 4) + c;
        #pragma unroll
        for (int ks = 0; ks < 2; ks++) {
            bL[ct][ks] = *(const s8v*)(Wlt + ((u32)col << 6) + (ks << 5) + (kg << 3));
            bR[ct][ks] = *(const s8v*)(Wrt + ((u32)col << 6) + (ks << 5) + (kg << 3));
        }
        blv[ct] = bl[col];
        brv[ct] = br[col];
    }
    const int NTILES = N_NODES / 16;   // 3125
    for (int t = blockIdx.x; t < NTILES; t += gridDim.x) {
        int nb = t << 4;
        int xi = x[nb + c];
        const u16* er = embb + ((u32)xi << 6);
        s8v a0 = *(const s8v*)(er + (kg << 3));
        s8v a1 = *(const s8v*)(er + 32 + (kg << 3));
        #pragma unroll
        for (int ct = 0; ct < 4; ct++) {
            int col = (w << 6) + (ct << 4) + c;
            f4 accL = {blv[ct], blv[ct], blv[ct], blv[ct]};
            f4 accR = {brv[ct], brv[ct], brv[ct], brv[ct]};
            accL = __builtin_amdgcn_mfma_f32_16x16x32_bf16(a0, bL[ct][0], accL, 0, 0, 0);
            accL = __builtin_amdgcn_mfma_f32_16x16x32_bf16(a1, bL[ct][1], accL, 0, 0, 0);
            accR = __builtin_amdgcn_mfma_f32_16x16x32_bf16(a0, bR[ct][0], accR, 0, 0, 0);
            accR = __builtin_amdgcn_mfma_f32_16x16x32_bf16(a1, bR[ct][1], accR, 0, 0, 0);
            #pragma unroll
            for (int i = 0; i < 4; i++) {
                int node = nb + (kg << 2) + i;
                xl[((size_t)node << 8) + col] = f2b(accL[i]);
                xr[((size_t)node << 8) + col] = f2b(accR[i]);
            }
        }
    }
}

// ======================= conv1 edge logits via MFMA (index+bfrag prefetch) ============
__global__ __launch_bounds__(256) void k_logits1(
    const int2* __restrict__ epk, const int* __restrict__ dstc,
    const u32* __restrict__ eah, const u16* __restrict__ xl, const u16* __restrict__ xr,
    const u32* __restrict__ Weh, const float* __restrict__ atts,
    float* __restrict__ Lg)
{
    int lane = threadIdx.x & 63;
    int er = lane & 15, grp = lane >> 4;
    hf8 wA[16];
    #pragma unroll
    for (int ct = 0; ct < 16; ct++) {
        uint4 q;
        q.x = Weh[(grp * 4 + 0) * 256 + ct * 16 + er];
        q.y = Weh[(grp * 4 + 1) * 256 + ct * 16 + er];
        q.z = Weh[(grp * 4 + 2) * 256 + ct * 16 + er];
        q.w = Weh[(grp * 4 + 3) * 256 + ct * 16 + er];
        wA[ct] = __builtin_bit_cast(hf8, q);
    }
    int wid = blockIdx.x * 4 + (threadIdx.x >> 6);
    int nw = gridDim.x * 4;
    const int NT = N_EDGES / 16;
    const char* eab = (const char*)eah;
    const f4 zero = {0.f, 0.f, 0.f, 0.f};
    if (wid >= NT) return;
    int2 p = epk[wid * 16 + er];
    int d = dstc[wid * 16 + er];
    hf8 bfrag = *(const hf8*)(eab + (u32)p.x + (grp << 4));
    for (int t = wid; t < NT; t += nw) {
        int tn = t + nw;
        int2 pn; int dn; hf8 bfn;
        if (tn < NT) {
            pn = epk[tn * 16 + er];
            dn = dstc[tn * 16 + er];
            bfn = *(const hf8*)(eab + (u32)pn.x + (grp << 4));
        }
        int j = t * 16 + er;
        const u16* xlp = xl + ((u32)p.y << 8);
        const u16* xrp = xr + ((u32)d << 8);
        float part0 = 0.f, part1 = 0.f, part2 = 0.f, part3 = 0.f;
        #pragma unroll
        for (int ct = 0; ct < 16; ct++) {
            int c0 = ct * 16 + grp * 4;
            f4 z = __builtin_amdgcn_mfma_f32_16x16x32_f16(wA[ct], bfrag, zero, 0, 0, 0);
            uint2 ql = *(const uint2*)(xlp + c0);
            uint2 qr = *(const uint2*)(xrp + c0);
            float4 av = *(const float4*)(atts + c0);
            float z0 = z[0] + __uint_as_float(ql.x << 16)        + __uint_as_float(qr.x << 16);
            float z1 = z[1] + __uint_as_float(ql.x & 0xFFFF0000u) + __uint_as_float(qr.x & 0xFFFF0000u);
            float z2 = z[2] + __uint_as_float(ql.y << 16)        + __uint_as_float(qr.y << 16);
            float z3 = z[3] + __uint_as_float(ql.y & 0xFFFF0000u) + __uint_as_float(qr.y & 0xFFFF0000u);
            float s = av.x * fmaxf(z0, NEG * z0) + av.y * fmaxf(z1, NEG * z1)
                    + av.z * fmaxf(z2, NEG * z2) + av.w * fmaxf(z3, NEG * z3);
            if      (ct < 4)  part0 += s;
            else if (ct < 8)  part1 += s;
            else if (ct < 12) part2 += s;
            else              part3 += s;
        }
        part0 += __shfl_xor(part0, 16); part0 += __shfl_xor(part0, 32);
        part1 += __shfl_xor(part1, 16); part1 += __shfl_xor(part1, 32);
        part2 += __shfl_xor(part2, 16); part2 += __shfl_xor(part2, 32);
        part3 += __shfl_xor(part3, 16); part3 += __shfl_xor(part3, 32);
        float v01 = (grp & 1) ? part1 : part0;
        float v23 = (grp & 1) ? part3 : part2;
        float v = (grp & 2) ? v23 : v01;
        Lg[((size_t)j << 2) + grp] = v;   // [j][h] layout, coalesced 256B/wave
        p = pn; d = dn; bfrag = bfn;
    }
}

// ======================= conv1 fused: wave = node, lane = 4 cols ===================
// Per edge: one 512B wave-read of the xl row (uint2/lane) instead of 4x128B; Lg/epk
// are group-broadcast loads; Spart via pure shuffle-reduce (no LDS, no syncthreads).
__global__ __launch_bounds__(256) void k_fused1(
    const int* __restrict__ rowptr, const int2* __restrict__ epk,
    const float* __restrict__ Lg, const u16* __restrict__ xl,
    const float* __restrict__ bias, u16* __restrict__ out, float* __restrict__ Spart)
{
    int w = threadIdx.x >> 6, lane = threadIdx.x & 63;
    int node = blockIdx.x * 4 + w;
    int h = lane >> 4;              // head owning cols 4*lane..4*lane+3
    int c0 = lane << 2;
    int beg = rowptr[node], end = rowptr[node + 1];
    float a0 = 0.f, a1 = 0.f, a2 = 0.f, a3 = 0.f, dtot = 0.f;
    int j = beg;
    for (; j + 3 < end; j += 4) {
        int2 pA = epk[j], pB = epk[j + 1], pC = epk[j + 2], pD = epk[j + 3];
        float gA = Lg[((size_t)j << 2) + h];
        float gB = Lg[((size_t)(j + 1) << 2) + h];
        float gC = Lg[((size_t)(j + 2) << 2) + h];
        float gD = Lg[((size_t)(j + 3) << 2) + h];
        uint2 xA = *(const uint2*)(xl + ((u32)pA.y << 8) + c0);
        uint2 xB = *(const uint2*)(xl + ((u32)pB.y << 8) + c0);
        uint2 xC = *(const uint2*)(xl + ((u32)pC.y << 8) + c0);
        uint2 xD = *(const uint2*)(xl + ((u32)pD.y << 8) + c0);
        float eA = exp2f(gA), eB = exp2f(gB), eC = exp2f(gC), eD = exp2f(gD);
        a0 += (eA * b2f((u16)xA.x) + eB * b2f((u16)xB.x)) + (eC * b2f((u16)xC.x) + eD * b2f((u16)xD.x));
        a1 += (eA * b2f((u16)(xA.x >> 16)) + eB * b2f((u16)(xB.x >> 16)))
            + (eC * b2f((u16)(xC.x >> 16)) + eD * b2f((u16)(xD.x >> 16)));
        a2 += (eA * b2f((u16)xA.y) + eB * b2f((u16)xB.y)) + (eC * b2f((u16)xC.y) + eD * b2f((u16)xD.y));
        a3 += (eA * b2f((u16)(xA.y >> 16)) + eB * b2f((u16)(xB.y >> 16)))
            + (eC * b2f((u16)(xC.y >> 16)) + eD * b2f((u16)(xD.y >> 16)));
        dtot += (eA + eB) + (eC + eD);
    }
    for (; j < end; j++) {
        int2 p = epk[j];
        float e = exp2f(Lg[((size_t)j << 2) + h]);
        uint2 xv = *(const uint2*)(xl + ((u32)p.y << 8) + c0);
        a0 += e * b2f((u16)xv.x);
        a1 += e * b2f((u16)(xv.x >> 16));
        a2 += e * b2f((u16)xv.y);
        a3 += e * b2f((u16)(xv.y >> 16));
        dtot += e;
    }
    float inv = (end > beg) ? 1.f / (dtot + EPS_SM) : 0.f;
    float4 bv = *(const float4*)(bias + c0);
    float o0 = a0 * inv + bv.x;
    float o1 = a1 * inv + bv.y;
    float o2 = a2 * inv + bv.z;
    float o3 = a3 * inv + bv.w;
    u32 lo = (u32)f2b(o0) | ((u32)f2b(o1) << 16);
    u32 hi = (u32)f2b(o2) | ((u32)f2b(o3) << 16);
    *(uint2*)(out + ((size_t)node << 8) + c0) = make_uint2(lo, hi);
    float s1 = (o0 + o1) + (o2 + o3);
    float s2 = (o0 * o0 + o1 * o1) + (o2 * o2 + o3 * o3);
    #pragma unroll
    for (int off = 32; off; off >>= 1) { s1 += __shfl_xor(s1, off); s2 += __shfl_xor(s2, off); }
    if (lane == 0) {
        Spart[(size_t)node * 2]     = s1;
        Spart[(size_t)node * 2 + 1] = s2;
    }
}

// ======================= LayerNorm apply (+ReLU) in-place on bf16 =======================
__global__ void k_ln_apply_relu_b(
    u16* v, const float* __restrict__ w, const float* __restrict__ b,
    const float* __restrict__ S, int M, int C)
{
    int i = blockIdx.x * blockDim.x + threadIdx.x;
    if (i >= M) return;
    float mu = S[0] / (float)M;
    float var = S[1] / (float)M - mu * mu;
    float inv = 1.f / (sqrtf(fmaxf(var, 0.f)) + EPS_LN);
    int c = i % C;
    float y = (b2f(v[i]) - mu) * inv * w[c] + b[c];
    v[i] = f2b(fmaxf(y, 0.f));
}

__global__ void k_ln_out(
    const float* __restrict__ v, const float* __restrict__ w, const float* __restrict__ b,
    const float* __restrict__ S, int M, int C, float* __restrict__ out)
{
    int i = blockIdx.x * blockDim.x + threadIdx.x;
    if (i >= M) return;
    float mu = S[0] / (float)M;
    float var = S[1] / (float)M - mu * mu;
    float inv = 1.f / (sqrtf(fmaxf(var, 0.f)) + EPS_LN);
    int c = i % C;
    out[i] = (v[i] - mu) * inv * w[c] + b[c];
}

// ======================= conv2 node transform via MFMA (bf16 rows padded to 64) =========
__global__ __launch_bounds__(256) void k_node2(
    const u16* __restrict__ h, const u16* __restrict__ Wlt, const u16* __restrict__ Wrt,
    const float* __restrict__ bl, const float* __restrict__ br,
    u16* __restrict__ xlb, u16* __restrict__ xrb)
{
    int w = threadIdx.x >> 6, lane = threadIdx.x & 63;
    int c = lane & 15, kg = lane >> 4;
    int col = (w << 4) + c;                       // 0..63
    s8v bL[8], bR[8];
    #pragma unroll
    for (int ks = 0; ks < 8; ks++) {
        bL[ks] = *(const s8v*)(Wlt + ((u32)col << 8) + (ks << 5) + (kg << 3));
        bR[ks] = *(const s8v*)(Wrt + ((u32)col << 8) + (ks << 5) + (kg << 3));
    }
    float blv = (col < OUTD) ? bl[col] : 0.f;
    float brv = (col < OUTD) ? br[col] : 0.f;
    const int NTILES = N_NODES / 16;   // 3125
    for (int t = blockIdx.x; t < NTILES; t += gridDim.x) {
        int nb = t << 4;
        const u16* hrow = h + ((size_t)(nb + c) << 8) + (kg << 3);
        f4 accL = {blv, blv, blv, blv};
        f4 accR = {brv, brv, brv, brv};
        #pragma unroll
        for (int ks = 0; ks < 8; ks++) {
            s8v a = *(const s8v*)(hrow + (ks << 5));
            accL = __builtin_amdgcn_mfma_f32_16x16x32_bf16(a, bL[ks], accL, 0, 0, 0);
            accR = __builtin_amdgcn_mfma_f32_16x16x32_bf16(a, bR[ks], accR, 0, 0, 0);
        }
        #pragma unroll
        for (int i = 0; i < 4; i++) {
            int node = nb + (kg << 2) + i;
            xlb[((u32)node << 6) + col] = f2b(accL[i]);
            xrb[((u32)node << 6) + col] = f2b(accR[i]);
        }
    }
}

// ======================= conv2 edge logits via MFMA (index+bfrag prefetch) ==========
__global__ __launch_bounds__(256) void k_logits2(
    const int2* __restrict__ epk, const int* __restrict__ dstc,
    const u32* __restrict__ eah, const u16* __restrict__ xlb, const u16* __restrict__ xrb,
    const u32* __restrict__ Weh, const float* __restrict__ atts,
    float* __restrict__ Lg2)
{
    int lane = threadIdx.x & 63;
    int er = lane & 15, grp = lane >> 4;
    hf8 wA[4];
    #pragma unroll
    for (int ct = 0; ct < 4; ct++) {
        uint4 q;
        q.x = Weh[(grp * 4 + 0) * 64 + ct * 16 + er];
        q.y = Weh[(grp * 4 + 1) * 64 + ct * 16 + er];
        q.z = Weh[(grp * 4 + 2) * 64 + ct * 16 + er];
        q.w = Weh[(grp * 4 + 3) * 64 + ct * 16 + er];
        wA[ct] = __builtin_bit_cast(hf8, q);
    }
    int wid = blockIdx.x * 4 + (threadIdx.x >> 6);
    int nw = gridDim.x * 4;
    const int NT = N_EDGES / 16;
    const char* eab = (const char*)eah;
    const f4 zero = {0.f, 0.f, 0.f, 0.f};
    if (wid >= NT) return;
    int2 p = epk[wid * 16 + er];
    int d = dstc[wid * 16 + er];
    hf8 bfrag = *(const hf8*)(eab + (u32)p.x + (grp << 4));
    for (int t = wid; t < NT; t += nw) {
        int tn = t + nw;
        int2 pn; int dn; hf8 bfn;
        if (tn < NT) {
            pn = epk[tn * 16 + er];
            dn = dstc[tn * 16 + er];
            bfn = *(const hf8*)(eab + (u32)pn.x + (grp << 4));
        }
        int j = t * 16 + er;
        const u16* xlp = xlb + ((u32)p.y << 6);
        const u16* xrp = xrb + ((u32)d << 6);
        float tot = 0.f;
        #pragma unroll
        for (int ct = 0; ct < 4; ct++) {
            int c0 = ct * 16 + grp * 4;
            f4 z = __builtin_amdgcn_mfma_f32_16x16x32_f16(wA[ct], bfrag, zero, 0, 0, 0);
            uint2 ql = *(const uint2*)(xlp + c0);
            uint2 qr = *(const uint2*)(xrp + c0);
            float4 av = *(const float4*)(atts + c0);
            float z0 = z[0] + __uint_as_float(ql.x << 16)        + __uint_as_float(qr.x << 16);
            float z1 = z[1] + __uint_as_float(ql.x & 0xFFFF0000u) + __uint_as_float(qr.x & 0xFFFF0000u);
            float z2 = z[2] + __uint_as_float(ql.y << 16)        + __uint_as_float(qr.y << 16);
            float z3 = z[3] + __uint_as_float(ql.y & 0xFFFF0000u) + __uint_as_float(qr.y & 0xFFFF0000u);
            tot += av.x * fmaxf(z0, NEG * z0) + av.y * fmaxf(z1, NEG * z1)
                 + av.z * fmaxf(z2, NEG * z2) + av.w * fmaxf(z3, NEG * z3);
        }
        tot += __shfl_xor(tot, 16);
        tot += __shfl_xor(tot, 32);
        if (lane < 16) Lg2[j] = tot;   // 64B coalesced per tile
        p = pn; d = dn; bfrag = bfn;
    }
}

// ======================= conv2 fused (light): softmax + aggregate only ===========
__global__ __launch_bounds__(256) void k_fused2(
    const int* __restrict__ rowptr, const int2* __restrict__ epk,
    const float* __restrict__ Lg2, const u16* __restrict__ xlb,
    const float* __restrict__ bias, float* __restrict__ out, float* __restrict__ Spart)
{
    int w = threadIdx.x >> 6, lane = threadIdx.x & 63;
    int node = blockIdx.x * 4 + w;
    bool col = lane < OUTD;
    int beg = rowptr[node], end = rowptr[node + 1];
    float acc = 0.f, dtot = 0.f;
    int j = beg;
    for (; j + 3 < end; j += 4) {
        int2 p0 = epk[j], p1 = epk[j + 1], p2 = epk[j + 2], p3 = epk[j + 3];
        float g0 = Lg2[j], g1 = Lg2[j + 1], g2 = Lg2[j + 2], g3 = Lg2[j + 3];
        float x0 = b2f(xlb[((u32)p0.y << 6) + lane]);
        float x1 = b2f(xlb[((u32)p1.y << 6) + lane]);
        float x2 = b2f(xlb[((u32)p2.y << 6) + lane]);
        float x3 = b2f(xlb[((u32)p3.y << 6) + lane]);
        float e0 = exp2f(g0), e1 = exp2f(g1), e2 = exp2f(g2), e3 = exp2f(g3);
        acc  += (e0 * x0 + e1 * x1) + (e2 * x2 + e3 * x3);
        dtot += (e0 + e1) + (e2 + e3);
    }
    for (; j < end; j++) {
        int2 p = epk[j];
        float e = exp2f(Lg2[j]);
        float xv = b2f(xlb[((u32)p.y << 6) + lane]);
        acc += e * xv; dtot += e;
    }
    float s1 = 0.f, s2 = 0.f;
    if (col) {
        float o = ((end > beg) ? acc / (dtot + EPS_SM) : 0.f) + bias[lane];
        out[(u32)node * OUTD + lane] = o;
        s1 = o; s2 = o * o;
    }
    #pragma unroll
    for (int off = 32; off; off >>= 1) { s1 += __shfl_xor(s1, off); s2 += __shfl_xor(s2, off); }
    __shared__ float ls1[4], ls2[4];
    if (lane == 0) { ls1[w] = s1; ls2[w] = s2; }
    __syncthreads();
    if (threadIdx.x == 0) {
        Spart[(size_t)blockIdx.x * 2]     = ls1[0] + ls1[1] + ls1[2] + ls1[3];
        Spart[(size_t)blockIdx.x * 2 + 1] = ls2[0] + ls2[1] + ls2[2] + ls2[3];
    }
}

extern "C" void kernel_launch(void* const* d_in, const int* in_sizes, int n_in,
                              void* d_out, int out_size, void* d_ws, size_t ws_size,
                              hipStream_t stream)
{
    const int*   x    = (const int*)d_in[0];
    const int*   ei   = (const int*)d_in[1];
    const int*   srcA = ei;
    const int*   dstA = ei + N_EDGES;
    const float* ea   = (const float*)d_in[2];
    const float* emb  = (const float*)d_in[3];
    const float* Wl1  = (const float*)d_in[4];
    const float* bl1  = (const float*)d_in[5];
    const float* Wr1  = (const float*)d_in[6];
    const float* br1  = (const float*)d_in[7];
    const float* We1  = (const float*)d_in[8];
    const float* att1 = (const float*)d_in[9];
    const float* bias1= (const float*)d_in[10];
    const float* ln1w = (const float*)d_in[11];
    const float* ln1b = (const float*)d_in[12];
    const float* Wl2  = (const float*)d_in[13];
    const float* bl2  = (const float*)d_in[14];
    const float* Wr2  = (const float*)d_in[15];
    const float* br2  = (const float*)d_in[16];
    const float* We2  = (const float*)d_in[17];
    const float* att2 = (const float*)d_in[18];
    const float* bias2= (const float*)d_in[19];
    const float* ln2w = (const float*)d_in[20];
    const float* ln2b = (const float*)d_in[21];

    // workspace layout (float-slot offsets); peak 31,000,000 slots = 124.0 MB
    float* W = (float*)d_ws;
    u16*   xl1b    = (u16*)W;                      // [0, 6.4M)
    u16*   xr1b    = (u16*)(W + 6400000);          // [6.4M, 12.8M)
    u16*   out1b   = (u16*)(W + 12800000);         // [12.8M, 19.2M)  bf16, h1 in place
    u32*   eah     = (u32*)(W + 19200000);         // E*16 u32 [19.2M, 27.2M)
    int2*  epk     = (int2*)(W + 27200000);        // [27.2M, 28.2M)
    int*   rowptr  = (int*)(W + 28200000);         // 50,001 ints, 60k slots
    int*   cnt     = (int*)(W + 28260000);         // N
    int*   cursor  = (int*)(W + 28310000);         // N
    float* Spart   = W + 28360000;                 // 2*N [28.36M, 28.46M)
    float* S       = W + 28460000;                 // 4
    int*   bsum    = (int*)(W + 28461000);         // SCAN_B=196 ints — gap before Weh1
    u32*   Weh1    = (u32*)(W + 28470000);         // 16*256 = 4096 (k2>=14 zero)
    u32*   Weh2    = (u32*)(W + 28480000);         // 16*64  = 1024 (padded)
    float* atts1   = W + 28481100;                 // 256
    float* atts2   = W + 28481600;                 // 64
    int*   dstc    = (int*)(W + 28482000);         // E ints = 500k slots [28.482M, 28.982M)
    u16*   Wlt2    = (u16*)(W + 28982000);         // 64*256 u16 = 8192 slots [28.982M, 28.9902M)
    u16*   Wrt2    = (u16*)(W + 28991000);         // 64*256 u16 = 8192 slots [28.991M, 28.9992M)
    float* Lg      = W + 29000000;                 // E*4 f32 [29M, 31M)  (conv1, written by logits1)
    // pre-conv1 transients (dead before logits1 writes Lg; parked inside Lg region):
    u16*   embb    = (u16*)(W + 29000000);         // N*64 u16 = 1.6M slots [29.0M, 30.6M)
    u16*   Wlt1    = (u16*)(W + 30600000);         // 256*64 u16 = 8192 slots
    u16*   Wrt1    = (u16*)(W + 30610000);         // 256*64 u16 = 8192 slots
    // conv2 reuse (liveness: xl1b/xr1b dead after fused1; Lg dead after fused1):
    u16*   xl2b    = (u16*)W;                      // N*64 u16 [0, 1.6M)
    u16*   xr2b    = (u16*)(W + 1600000);          // N*64 u16 [1.6M, 3.2M)
    float* out2    = W + 3200000;                  // N*50 f32 [3.2M, 5.7M)
    float* Lg2     = W + 29000000;                 // E f32 (reuses Lg region)
    u16*   h1      = out1b;

    // init (zeroing + ea f16 + We f16 pack + emb bf16 pack + att*log2e) + W transpose pack + CSR
    k_init<<<(N_EDGES * 8 + 255) / 256, 256, 0, stream>>>(cnt, cursor, S, ea, eah,
                                                          We1, We2, Weh1, Weh2,
                                                          att1, att2, atts1, atts2,
                                                          emb, embb);
    k_packw<<<128, 256, 0, stream>>>(Wl1, Wr1, Wlt1, Wrt1, Wl2, Wr2, Wlt2, Wrt2);
    k_hist<<<(N_EDGES + 255) / 256, 256, 0, stream>>>(dstA, cnt);
    k_scan1<<<SCAN_B, 256, 0, stream>>>(cnt, bsum);
    k_scan2<<<1, 256, 0, stream>>>(bsum);
    k_scan3<<<SCAN_B, 256, 0, stream>>>(cnt, bsum, rowptr);
    k_scatter<<<(N_EDGES + 255) / 256, 256, 0, stream>>>(srcA, dstA, rowptr, cursor, epk, dstc);

    // conv1
    k_node1<<<1024, 256, 0, stream>>>(x, embb, Wlt1, Wrt1, bl1, br1, xl1b, xr1b);
    k_logits1<<<1024, 256, 0, stream>>>(epk, dstc, eah, xl1b, xr1b, Weh1, atts1, Lg);
    k_fused1<<<N_NODES / 4, 256, 0, stream>>>(rowptr, epk, Lg, xl1b, bias1, out1b, Spart);
    k_sumpart<<<32, 256, 0, stream>>>(Spart, N_NODES, S);
    k_ln_apply_relu_b<<<(N_NODES * F1 + 255) / 256, 256, 0, stream>>>(h1, ln1w, ln1b, S, N_NODES * F1, F1);

    // conv2
    k_node2<<<1024, 256, 0, stream>>>(h1, Wlt2, Wrt2, bl2, br2, xl2b, xr2b);
    k_logits2<<<1024, 256, 0, stream>>>(epk, dstc, eah, xl2b, xr2b, Weh2, atts2, Lg2);
    k_fused2<<<N_NODES / 4, 256, 0, stream>>>(rowptr, epk, Lg2, xl2b, bias2, out2, Spart);
    k_sumpart<<<32, 256, 0, stream>>>(Spart, N_NODES / 4, S + 2);
    k_ln_out<<<(N_NODES * OUTD + 255) / 256, 256, 0, stream>>>(out2, ln2w, ln2b, S + 2, N_NODES * OUTD, OUTD, (float*)d_out);
}